// Round 2
// 791.415 us; speedup vs baseline: 1.2323x; 1.2323x over previous
//
#include <hip/hip_runtime.h>

typedef unsigned short ushort_t;
typedef __bf16 bf16_t;
typedef __bf16 bf16x8_b __attribute__((ext_vector_type(8)));
typedef bf16x8_b __attribute__((may_alias)) bf16x8;
typedef unsigned short u16x8_b __attribute__((ext_vector_type(8)));
typedef u16x8_b __attribute__((may_alias)) u16x8;
typedef unsigned int u32x4_b __attribute__((ext_vector_type(4)));
typedef u32x4_b __attribute__((may_alias)) u32x4;
typedef float floatx4 __attribute__((ext_vector_type(4)));

__device__ __forceinline__ float bf2f(ushort_t h) {
    union { unsigned int u; float f; } v; v.u = ((unsigned int)h) << 16; return v.f;
}
__device__ __forceinline__ ushort_t f2bf(float f) {
    union { float f; unsigned int u; } v; v.f = f;
    unsigned int u = v.u;
    unsigned int r = (u + 0x7FFFu + ((u >> 16) & 1u)) >> 16;
    return (ushort_t)r;
}

// ---------------------------------------------------------------------------
// Input dtype sniff: flag=1 means fp32 inputs (verified on HW in round 5).
// ---------------------------------------------------------------------------
__global__ __launch_bounds__(256) void detect_dtype(
    const unsigned int* __restrict__ x, int* __restrict__ flag)
{
    __shared__ int cnt;
    if (threadIdx.x == 0) cnt = 0;
    __syncthreads();
    int c = 0;
    for (int i = threadIdx.x; i < 512; i += 256) {
        unsigned int w = x[i];
        unsigned int e = (w >> 7) & 0xFFu;
        if (e >= 0x70u && e <= 0x8Fu) ++c;
    }
    atomicAdd(&cnt, c);
    __syncthreads();
    if (threadIdx.x == 0) *flag = (cnt < 256) ? 1 : 0;
}

// ---------------------------------------------------------------------------
// Transpose+convert 6 weights [1024,1024] -> WT[z][n][k] = bf16(W[k][n])
// ---------------------------------------------------------------------------
__global__ __launch_bounds__(256) void conv_weights(
    const void* __restrict__ w0, const void* __restrict__ w1,
    const void* __restrict__ w2, const void* __restrict__ w3,
    const void* __restrict__ w4, const void* __restrict__ w5,
    ushort_t* __restrict__ WT, const int* __restrict__ flag)
{
    __shared__ ushort_t t[64][65];
    const int z = blockIdx.z;
    const void* src = (z == 0) ? w0 : (z == 1) ? w1 : (z == 2) ? w2
                    : (z == 3) ? w3 : (z == 4) ? w4 : w5;
    const bool isf = (*flag != 0);
    ushort_t* dst = WT + (size_t)z * 1024 * 1024;
    const int x0 = blockIdx.x * 64, y0 = blockIdx.y * 64;
    const int tx = threadIdx.x & 63, ty0 = threadIdx.x >> 6;
#pragma unroll
    for (int r = 0; r < 16; ++r) {
        int ty = ty0 * 16 + r;
        size_t idx = (size_t)(y0 + ty) * 1024 + x0 + tx;
        t[ty][tx] = isf ? f2bf(((const float*)src)[idx]) : ((const ushort_t*)src)[idx];
    }
    __syncthreads();
#pragma unroll
    for (int r = 0; r < 16; ++r) {
        int ty = ty0 * 16 + r;
        dst[(size_t)(x0 + ty) * 1024 + y0 + tx] = t[tx][ty];
    }
}

__global__ __launch_bounds__(256) void conv_bout(
    const void* __restrict__ bout, ushort_t* __restrict__ dst,
    const int* __restrict__ flag)
{
    const bool isf = (*flag != 0);
    for (int i = threadIdx.x; i < 1024; i += 256)
        dst[i] = isf ? f2bf(((const float*)bout)[i]) : ((const ushort_t*)bout)[i];
}

// ---------------------------------------------------------------------------
// Convert one 2-batch group slice of {h_t,h_a,h_v,h_hyper} to bf16 in ws.
// ---------------------------------------------------------------------------
__global__ __launch_bounds__(256) void conv_act(
    const void* __restrict__ h_t, const void* __restrict__ h_a,
    const void* __restrict__ h_v, const void* __restrict__ h_hyper,
    long off, ushort_t* __restrict__ ActC, const int* __restrict__ flag)
{
    const int z = blockIdx.y;
    const void* s = (z == 0) ? h_t : (z == 1) ? h_a : (z == 2) ? h_v : h_hyper;
    const size_t e8 = ((size_t)blockIdx.x * 256 + threadIdx.x) * 8;
    ushort_t* dst = ActC + (size_t)z * 2 * 1024 * 1024 + e8;
    if (*flag) {
        const float* f = (const float*)s + off + e8;
        u32x4 o;
#pragma unroll
        for (int j = 0; j < 4; ++j) {
            unsigned int lo = f2bf(f[2 * j]);
            unsigned int hi = f2bf(f[2 * j + 1]);
            o[j] = lo | (hi << 16);
        }
        *(u32x4*)dst = o;
    } else {
        const ushort_t* b = (const ushort_t*)s + off + e8;
        *(u32x4*)dst = *(const u32x4*)b;
    }
}

// ---------------------------------------------------------------------------
// Core GEMM: C[M,1024] = A[M,1024] @ B, BT[1024,1024] given. Tile 128x128.
// ---------------------------------------------------------------------------
__device__ __forceinline__ void gemm_core(
    const ushort_t* __restrict__ A, const ushort_t* __restrict__ BT,
    void* __restrict__ C, size_t ooff, bool f32o,
    const ushort_t* __restrict__ addmat, const ushort_t* __restrict__ bias)
{
    constexpr int K = 1024, N = 1024;
    __shared__ __align__(16) ushort_t As[128 * 32];  // [m][k]
    __shared__ __align__(16) ushort_t Bs[128 * 32];  // [n][k]
    const int tid = threadIdx.x;
    const int w = tid >> 6, lane = tid & 63;
    const int g = lane >> 4, c = lane & 15;
    const int m0 = blockIdx.y * 128, n0 = blockIdx.x * 128;
    const int wm = (w >> 1) * 64, wn = (w & 1) * 64;

    floatx4 acc[4][4];
#pragma unroll
    for (int i = 0; i < 4; ++i)
#pragma unroll
        for (int j = 0; j < 4; ++j) acc[i][j] = (floatx4)0.0f;

    for (int k0 = 0; k0 < K; k0 += 32) {
        u32x4 va[2], vb[2];
#pragma unroll
        for (int r = 0; r < 2; ++r) {
            const int row = (w * 2 + r) * 16 + (lane >> 2);
            const int kc = k0 + (lane & 3) * 8;
            va[r] = *(const u32x4*)(A + (size_t)(m0 + row) * K + kc);
            vb[r] = *(const u32x4*)(BT + (size_t)(n0 + row) * K + kc);
        }
        __syncthreads();
#pragma unroll
        for (int r = 0; r < 2; ++r) {
            *(u32x4*)&As[(w * 2 + r) * 512 + lane * 8] = va[r];
            *(u32x4*)&Bs[(w * 2 + r) * 512 + lane * 8] = vb[r];
        }
        __syncthreads();
        bf16x8 af[4], bfr[4];
#pragma unroll
        for (int i = 0; i < 4; ++i)
            af[i] = *(const bf16x8*)&As[(wm + i * 16 + c) * 32 + g * 8];
#pragma unroll
        for (int j = 0; j < 4; ++j)
            bfr[j] = *(const bf16x8*)&Bs[(wn + j * 16 + c) * 32 + g * 8];
#pragma unroll
        for (int i = 0; i < 4; ++i)
#pragma unroll
            for (int j = 0; j < 4; ++j)
                acc[i][j] = __builtin_amdgcn_mfma_f32_16x16x32_bf16(
                    af[i], bfr[j], acc[i][j], 0, 0, 0);
    }
#pragma unroll
    for (int i = 0; i < 4; ++i) {
#pragma unroll
        for (int j = 0; j < 4; ++j) {
            const int gc = n0 + wn + j * 16 + c;
#pragma unroll
            for (int r = 0; r < 4; ++r) {
                const int gr = m0 + wm + i * 16 + g * 4 + r;
                float v = acc[i][j][r];
                if (addmat)
                    v += bf2f(addmat[(size_t)gr * N + gc]) + bf2f(bias[gc]);
                const size_t idx = ooff + (size_t)gr * N + gc;
                if (f32o) ((float*)C)[idx] = v;
                else      ((ushort_t*)C)[idx] = f2bf(v);
            }
        }
    }
}

__global__ __launch_bounds__(256) void gemm_proj(
    const ushort_t* __restrict__ ActC, const ushort_t* __restrict__ WT,
    ushort_t* __restrict__ Pbuf)
{
    const int z = blockIdx.z;
    const int asel = (z == 0) ? 0 : (z <= 2 ? 1 : 2);
    // WT order: 0 Wq, 1 Wk_ta, 2 Wk_tv, 3 Wv_ta, 4 Wv_tv, 5 Wout
    const int wsel = (z == 2) ? 3 : ((z == 3) ? 2 : z);
    gemm_core(ActC + (size_t)asel * 2 * 1024 * 1024,
              WT + (size_t)wsel * 1024 * 1024,
              Pbuf + (size_t)z * 2 * 1024 * 1024, 0, false, nullptr, nullptr);
}

__global__ __launch_bounds__(256) void gemm_out(
    const ushort_t* __restrict__ OutSum, const ushort_t* __restrict__ WoutT,
    const ushort_t* __restrict__ hyperC, const ushort_t* __restrict__ boutC,
    void* __restrict__ out, long ooff, const int* __restrict__ flag)
{
    gemm_core(OutSum, WoutT, out, (size_t)ooff, (*flag != 0), hyperC, boutC);
}

// ---------------------------------------------------------------------------
// Fused dual-stream MFMA flash attention, round-7:
//  - both streams (ta/tv) in one kt loop, 2 barriers per fused tile (was 6)
//  - register prefetch of next K/V tiles (T14): global latency off the chain
//  - Q fragments hoisted to registers (pre-scaled), staged once via Ks[0]
//  - Ks/Ps stride 72 (conflict-free b128 reads / 2-way-free scalar writes)
//  - V gather de-conflicted by granule XOR swizzle: row j's logical 16-col
//    granule p stored at physical granule (p + (j>>3)) & 3, stride 64.
//    Read of V[j][dt*16+c] -> elem j*64 + ((dt + (j>>3))&3)*16 + c; within one
//    gather instruction all 64 lanes hit distinct elem%64 slots => no bank
//    conflict (was 8-way). Write side applies the same involution at 16B
//    granularity, stays 16B-aligned. (PV = proven scalar-gather math from the
//    974us kernel; tr_b16 experiment reverted after R0 correctness failure.)
//  - blockIdx: x=head, y=q-tile so the 16 blocks sharing a K/V stripe map to
//    one XCD (id%8 == h%8) for L2 locality
// ---------------------------------------------------------------------------
__global__ __launch_bounds__(256) void attn_fused(
    const ushort_t* __restrict__ Qb,
    const ushort_t* __restrict__ Kta, const ushort_t* __restrict__ Vta,
    const ushort_t* __restrict__ Ktv, const ushort_t* __restrict__ Vtv,
    ushort_t* __restrict__ Osum)
{
    const int h = blockIdx.x, qb = blockIdx.y, lb = blockIdx.z;
    const int tid = threadIdx.x, w = tid >> 6, lane = tid & 63;
    const int g = lane >> 4, c = lane & 15;

    __shared__ __align__(16) ushort_t Ks[2][64 * 72];   // K tiles [j][d] pad72
    __shared__ __align__(16) ushort_t Vs[2][64 * 64];   // V tiles, granule-swz
    __shared__ __align__(16) ushort_t Ps[2][4][16 * 72];// per-stream per-wave P

    const float qscale = 0.125f * 1.44269504f;  // SCALE * log2(e)
    const size_t hcol = (size_t)h * 64;
    const size_t kbase = (size_t)lb * 1024;

    // staging coords: row sj (0..31 per half), 8 contiguous cols at sd
    const int sj = tid >> 3;
    const int sd = (tid & 7) * 8;

    const ushort_t* Kp[2] = { Kta, Ktv };
    const ushort_t* Vv[2] = { Vta, Vtv };

    // ---- prefetch kt=0 tiles into registers (in flight during Q setup)
    u32x4 pk[2][2], pv[2][2];
#pragma unroll
    for (int s = 0; s < 2; ++s)
#pragma unroll
        for (int r = 0; r < 2; ++r) {
            const size_t row = kbase + r * 32 + sj;
            pk[s][r] = *(const u32x4*)(Kp[s] + row * 1024 + hcol + sd);
            pv[s][r] = *(const u32x4*)(Vv[s] + row * 1024 + hcol + sd);
        }

    // ---- stage Q through Ks[0]; hoist pre-scaled fragments to registers
    bf16x8 aq[2];
    {
        const size_t qrow0 = kbase + qb * 64;
#pragma unroll
        for (int r = 0; r < 2; ++r)
            *(u32x4*)&Ks[0][(r * 32 + sj) * 72 + sd] =
                *(const u32x4*)(Qb + (qrow0 + r * 32 + sj) * 1024 + hcol + sd);
        __syncthreads();
#pragma unroll
        for (int dh = 0; dh < 2; ++dh) {
            u16x8 raw = *(const u16x8*)&Ks[0][(w * 16 + c) * 72 + dh * 32 + g * 8];
            u16x8 sc;
#pragma unroll
            for (int e = 0; e < 8; ++e) sc[e] = f2bf(bf2f(raw[e]) * qscale);
            aq[dh] = __builtin_bit_cast(bf16x8_b, (u16x8_b)sc);
        }
    }

    floatx4 O[2][4];
    float m[2][4], l[2][4];
#pragma unroll
    for (int s = 0; s < 2; ++s) {
#pragma unroll
        for (int dt = 0; dt < 4; ++dt) O[s][dt] = (floatx4)0.0f;
#pragma unroll
        for (int r = 0; r < 4; ++r) { m[s][r] = -1e30f; l[s][r] = 0.0f; }
    }

    for (int kt = 0; kt < 16; ++kt) {
        __syncthreads();  // previous tile's LDS reads complete
        // write staged tiles (compiler inserts vmcnt wait for pk/pv)
#pragma unroll
        for (int s = 0; s < 2; ++s)
#pragma unroll
            for (int r = 0; r < 2; ++r) {
                const int j = r * 32 + sj;
                *(u32x4*)&Ks[s][j * 72 + sd] = pk[s][r];
                // granule swizzle: logical granule sd>>4 -> (sd>>4 + (j>>3))&3
                *(u32x4*)&Vs[s][j * 64 + ((((sd >> 4) + (j >> 3)) & 3) << 4)
                                + (sd & 8)] = pv[s][r];
            }
        // issue next tile's global loads; land during this tile's compute
        if (kt < 15) {
            const size_t krow0 = kbase + (size_t)(kt + 1) * 64;
#pragma unroll
            for (int s = 0; s < 2; ++s)
#pragma unroll
                for (int r = 0; r < 2; ++r) {
                    const size_t row = krow0 + r * 32 + sj;
                    pk[s][r] = *(const u32x4*)(Kp[s] + row * 1024 + hcol + sd);
                    pv[s][r] = *(const u32x4*)(Vv[s] + row * 1024 + hcol + sd);
                }
        }
        __syncthreads();  // tiles visible to all waves

        // ---- QK^T, both streams
        floatx4 S[2][4];
#pragma unroll
        for (int s = 0; s < 2; ++s)
#pragma unroll
            for (int jt = 0; jt < 4; ++jt) S[s][jt] = (floatx4)0.0f;
        __builtin_amdgcn_s_setprio(1);
#pragma unroll
        for (int s = 0; s < 2; ++s)
#pragma unroll
            for (int dh = 0; dh < 2; ++dh)
#pragma unroll
                for (int jt = 0; jt < 4; ++jt) {
                    bf16x8 bk = *(const bf16x8*)&Ks[s][(jt * 16 + c) * 72 + dh * 32 + g * 8];
                    S[s][jt] = __builtin_amdgcn_mfma_f32_16x16x32_bf16(
                        aq[dh], bk, S[s][jt], 0, 0, 0);
                }
        __builtin_amdgcn_s_setprio(0);

        // ---- online softmax + P store + O rescale, per stream
#pragma unroll
        for (int s = 0; s < 2; ++s) {
#pragma unroll
            for (int r = 0; r < 4; ++r) {
                float mx = fmaxf(fmaxf(S[s][0][r], S[s][1][r]), fmaxf(S[s][2][r], S[s][3][r]));
                mx = fmaxf(mx, __shfl_xor(mx, 1));
                mx = fmaxf(mx, __shfl_xor(mx, 2));
                mx = fmaxf(mx, __shfl_xor(mx, 4));
                mx = fmaxf(mx, __shfl_xor(mx, 8));
                const float mn = fmaxf(m[s][r], mx);
                const float al = __builtin_amdgcn_exp2f(m[s][r] - mn);
                m[s][r] = mn;
                float rs = 0.0f;
#pragma unroll
                for (int jt = 0; jt < 4; ++jt) {
                    const float p = __builtin_amdgcn_exp2f(S[s][jt][r] - mn);
                    Ps[s][w][(g * 4 + r) * 72 + jt * 16 + c] = f2bf(p);
                    rs += p;
                }
                rs += __shfl_xor(rs, 1); rs += __shfl_xor(rs, 2);
                rs += __shfl_xor(rs, 4); rs += __shfl_xor(rs, 8);
                l[s][r] = l[s][r] * al + rs;
#pragma unroll
                for (int dt = 0; dt < 4; ++dt) O[s][dt][r] *= al;
            }
        }

        // ---- PV, both streams. Ps is per-wave (same-wave DS ordering):
        //      no barrier needed between Ps write and read.
#pragma unroll
        for (int s = 0; s < 2; ++s) {
#pragma unroll
            for (int jh = 0; jh < 2; ++jh) {
                bf16x8 ap = *(const bf16x8*)&Ps[s][w][c * 72 + jh * 32 + g * 8];
                u16x8 bvu[4];
#pragma unroll
                for (int dt = 0; dt < 4; ++dt) {
#pragma unroll
                    for (int jj = 0; jj < 8; ++jj) {
                        const int j = jh * 32 + g * 8 + jj;
                        // physical granule = (dt + (j>>3)) & 3; (j>>3) folds
                        // to jh*4+g at compile time.
                        bvu[dt][jj] = Vs[s][j * 64 + (((dt + jh * 4 + g) & 3) << 4) + c];
                    }
                }
                __builtin_amdgcn_s_setprio(1);
#pragma unroll
                for (int dt = 0; dt < 4; ++dt) {
                    bf16x8 bv = __builtin_bit_cast(bf16x8_b, (u16x8_b)bvu[dt]);
                    O[s][dt] = __builtin_amdgcn_mfma_f32_16x16x32_bf16(
                        ap, bv, O[s][dt], 0, 0, 0);
                }
                __builtin_amdgcn_s_setprio(0);
            }
        }
    }

    // ---- epilogue: Osum = O_ta/l_ta + O_tv/l_tv
    const size_t orow0 = kbase + qb * 64 + w * 16;
#pragma unroll
    for (int dt = 0; dt < 4; ++dt)
#pragma unroll
        for (int r = 0; r < 4; ++r) {
            const float v = O[0][dt][r] / l[0][r] + O[1][dt][r] / l[1][r];
            Osum[(orow0 + g * 4 + r) * 1024 + hcol + dt * 16 + c] = f2bf(v);
        }
}

// ---------------------------------------------------------------------------
extern "C" void kernel_launch(void* const* d_in, const int* in_sizes, int n_in,
                              void* d_out, int out_size, void* d_ws, size_t ws_size,
                              hipStream_t stream)
{
    const void* h_t     = d_in[0];
    const void* h_a     = d_in[1];
    const void* h_v     = d_in[2];
    const void* h_hyper = d_in[3];
    const void* Wq      = d_in[4];
    const void* Wk_ta   = d_in[5];
    const void* Wk_tv   = d_in[6];
    const void* Wv_ta   = d_in[7];
    const void* Wv_tv   = d_in[8];
    const void* Wout    = d_in[9];
    const void* bout    = d_in[10];

    constexpr size_t MEG = (size_t)1024 * 1024;
    int*      flag  = (int*)d_ws;
    ushort_t* WT    = (ushort_t*)d_ws + 64;
    ushort_t* ActC  = WT + 6 * MEG;
    ushort_t* Pbuf  = ActC + 8 * MEG;
    ushort_t* OSg   = Pbuf + 10 * MEG;
    ushort_t* boutC = OSg + 2 * MEG;

    detect_dtype<<<1, 256, 0, stream>>>((const unsigned int*)h_t, flag);
    conv_weights<<<dim3(16, 16, 6), 256, 0, stream>>>(
        Wq, Wk_ta, Wk_tv, Wv_ta, Wv_tv, Wout, WT, flag);
    conv_bout<<<1, 256, 0, stream>>>(bout, boutC, flag);

    const long GSTRIDE = 2 * 1024 * 1024;
    for (int grp = 0; grp < 4; ++grp) {
        const long off = (long)grp * GSTRIDE;
        conv_act<<<dim3(1024, 4), 256, 0, stream>>>(
            h_t, h_a, h_v, h_hyper, off, ActC, flag);
        gemm_proj<<<dim3(8, 16, 5), 256, 0, stream>>>(ActC, WT, Pbuf);
        attn_fused<<<dim3(16, 16, 2), 256, 0, stream>>>(
            Pbuf,
            Pbuf + 1 * (size_t)GSTRIDE, Pbuf + 2 * (size_t)GSTRIDE,
            Pbuf + 3 * (size_t)GSTRIDE, Pbuf + 4 * (size_t)GSTRIDE,
            OSg);
        gemm_out<<<dim3(8, 16), 256, 0, stream>>>(
            OSg, WT + 5 * MEG, ActC + 6 * MEG, boutC,
            d_out, off, flag);
    }
}

// Round 3
// 783.924 us; speedup vs baseline: 1.2441x; 1.0096x over previous
//
#include <hip/hip_runtime.h>

typedef unsigned short ushort_t;
typedef __bf16 bf16_t;
typedef __bf16 bf16x8_b __attribute__((ext_vector_type(8)));
typedef bf16x8_b __attribute__((may_alias)) bf16x8;
typedef unsigned short u16x8_b __attribute__((ext_vector_type(8)));
typedef u16x8_b __attribute__((may_alias)) u16x8;
typedef unsigned int u32x4_b __attribute__((ext_vector_type(4)));
typedef u32x4_b __attribute__((may_alias)) u32x4;
typedef float floatx4 __attribute__((ext_vector_type(4)));

__device__ __forceinline__ float bf2f(ushort_t h) {
    union { unsigned int u; float f; } v; v.u = ((unsigned int)h) << 16; return v.f;
}
__device__ __forceinline__ ushort_t f2bf(float f) {
    union { float f; unsigned int u; } v; v.f = f;
    unsigned int u = v.u;
    unsigned int r = (u + 0x7FFFu + ((u >> 16) & 1u)) >> 16;
    return (ushort_t)r;
}

// Async global->LDS DMA, 16B per lane. Dest must be wave-uniform base; HW adds
// lane*16. Completion tracked by vmcnt; __syncthreads() drains it.
__device__ __forceinline__ void glds16(const ushort_t* g, ushort_t* l) {
    __builtin_amdgcn_global_load_lds(
        (const __attribute__((address_space(1))) unsigned int*)g,
        (__attribute__((address_space(3))) unsigned int*)l, 16, 0, 0);
}

// ---------------------------------------------------------------------------
// Input dtype sniff: flag=1 means fp32 inputs (verified on HW in round 5).
// ---------------------------------------------------------------------------
__global__ __launch_bounds__(256) void detect_dtype(
    const unsigned int* __restrict__ x, int* __restrict__ flag)
{
    __shared__ int cnt;
    if (threadIdx.x == 0) cnt = 0;
    __syncthreads();
    int c = 0;
    for (int i = threadIdx.x; i < 512; i += 256) {
        unsigned int w = x[i];
        unsigned int e = (w >> 7) & 0xFFu;
        if (e >= 0x70u && e <= 0x8Fu) ++c;
    }
    atomicAdd(&cnt, c);
    __syncthreads();
    if (threadIdx.x == 0) *flag = (cnt < 256) ? 1 : 0;
}

// ---------------------------------------------------------------------------
// Transpose+convert 6 weights [1024,1024] -> WT[z][n][k] = bf16(W[k][n])
// ---------------------------------------------------------------------------
__global__ __launch_bounds__(256) void conv_weights(
    const void* __restrict__ w0, const void* __restrict__ w1,
    const void* __restrict__ w2, const void* __restrict__ w3,
    const void* __restrict__ w4, const void* __restrict__ w5,
    ushort_t* __restrict__ WT, const int* __restrict__ flag)
{
    __shared__ ushort_t t[64][65];
    const int z = blockIdx.z;
    const void* src = (z == 0) ? w0 : (z == 1) ? w1 : (z == 2) ? w2
                    : (z == 3) ? w3 : (z == 4) ? w4 : w5;
    const bool isf = (*flag != 0);
    ushort_t* dst = WT + (size_t)z * 1024 * 1024;
    const int x0 = blockIdx.x * 64, y0 = blockIdx.y * 64;
    const int tx = threadIdx.x & 63, ty0 = threadIdx.x >> 6;
#pragma unroll
    for (int r = 0; r < 16; ++r) {
        int ty = ty0 * 16 + r;
        size_t idx = (size_t)(y0 + ty) * 1024 + x0 + tx;
        t[ty][tx] = isf ? f2bf(((const float*)src)[idx]) : ((const ushort_t*)src)[idx];
    }
    __syncthreads();
#pragma unroll
    for (int r = 0; r < 16; ++r) {
        int ty = ty0 * 16 + r;
        dst[(size_t)(x0 + ty) * 1024 + y0 + tx] = t[tx][ty];
    }
}

__global__ __launch_bounds__(256) void conv_bout(
    const void* __restrict__ bout, ushort_t* __restrict__ dst,
    const int* __restrict__ flag)
{
    const bool isf = (*flag != 0);
    for (int i = threadIdx.x; i < 1024; i += 256)
        dst[i] = isf ? f2bf(((const float*)bout)[i]) : ((const ushort_t*)bout)[i];
}

// ---------------------------------------------------------------------------
// Convert one 2-batch group slice of {h_t,h_a,h_v,h_hyper} to bf16 in ws.
// ---------------------------------------------------------------------------
__global__ __launch_bounds__(256) void conv_act(
    const void* __restrict__ h_t, const void* __restrict__ h_a,
    const void* __restrict__ h_v, const void* __restrict__ h_hyper,
    long off, ushort_t* __restrict__ ActC, const int* __restrict__ flag)
{
    const int z = blockIdx.y;
    const void* s = (z == 0) ? h_t : (z == 1) ? h_a : (z == 2) ? h_v : h_hyper;
    const size_t e8 = ((size_t)blockIdx.x * 256 + threadIdx.x) * 8;
    ushort_t* dst = ActC + (size_t)z * 2 * 1024 * 1024 + e8;
    if (*flag) {
        const float* f = (const float*)s + off + e8;
        u32x4 o;
#pragma unroll
        for (int j = 0; j < 4; ++j) {
            unsigned int lo = f2bf(f[2 * j]);
            unsigned int hi = f2bf(f[2 * j + 1]);
            o[j] = lo | (hi << 16);
        }
        *(u32x4*)dst = o;
    } else {
        const ushort_t* b = (const ushort_t*)s + off + e8;
        *(u32x4*)dst = *(const u32x4*)b;
    }
}

// ---------------------------------------------------------------------------
// Core GEMM: C[M,1024] = A[M,1024] @ B, BT[1024,1024] given. Tile 128x128.
// Round-8: staging via global_load_lds width=16 (m97 ladder step: the register
// staging path was VALU/issue-bound). Per K-step each wave issues 4 async DMA
// (16 rows x 32 cols each); __syncthreads() drains vmcnt. Fragment layout and
// MFMA order unchanged -> bit-identical output.
// ---------------------------------------------------------------------------
__device__ __forceinline__ void gemm_core(
    const ushort_t* __restrict__ A, const ushort_t* __restrict__ BT,
    void* __restrict__ C, size_t ooff, bool f32o,
    const ushort_t* __restrict__ addmat, const ushort_t* __restrict__ bias)
{
    constexpr int K = 1024, N = 1024;
    __shared__ __align__(16) ushort_t As[128 * 32];  // [m][k] linear
    __shared__ __align__(16) ushort_t Bs[128 * 32];  // [n][k] linear
    const int tid = threadIdx.x;
    const int w = tid >> 6, lane = tid & 63;
    const int g = lane >> 4, c = lane & 15;
    const int m0 = blockIdx.y * 128, n0 = blockIdx.x * 128;
    const int wm = (w >> 1) * 64, wn = (w & 1) * 64;

    // staging: wave w covers rows [w*32, w*32+32) in two 16-row DMA issues;
    // lane covers row base+(lane>>2), cols (lane&3)*8  (contiguous 1KB in LDS)
    const int srow = w * 32 + (lane >> 2);
    const int scol = (lane & 3) * 8;
    const ushort_t* Ag = A + (size_t)(m0 + srow) * K + scol;
    const ushort_t* Bg = BT + (size_t)(n0 + srow) * K + scol;
    ushort_t* AsW = &As[w * 1024];   // wave-uniform LDS dests
    ushort_t* BsW = &Bs[w * 1024];

    floatx4 acc[4][4];
#pragma unroll
    for (int i = 0; i < 4; ++i)
#pragma unroll
        for (int j = 0; j < 4; ++j) acc[i][j] = (floatx4)0.0f;

    for (int k0 = 0; k0 < K; k0 += 32) {
        __syncthreads();                 // prev tile's fragment reads done
        glds16(Ag + k0,            AsW);
        glds16(Ag + k0 + 16 * K,   AsW + 512);
        glds16(Bg + k0,            BsW);
        glds16(Bg + k0 + 16 * K,   BsW + 512);
        __syncthreads();                 // vmcnt drained by barrier semantics
        bf16x8 af[4], bfr[4];
#pragma unroll
        for (int i = 0; i < 4; ++i)
            af[i] = *(const bf16x8*)&As[(wm + i * 16 + c) * 32 + g * 8];
#pragma unroll
        for (int j = 0; j < 4; ++j)
            bfr[j] = *(const bf16x8*)&Bs[(wn + j * 16 + c) * 32 + g * 8];
#pragma unroll
        for (int i = 0; i < 4; ++i)
#pragma unroll
            for (int j = 0; j < 4; ++j)
                acc[i][j] = __builtin_amdgcn_mfma_f32_16x16x32_bf16(
                    af[i], bfr[j], acc[i][j], 0, 0, 0);
    }
#pragma unroll
    for (int i = 0; i < 4; ++i) {
#pragma unroll
        for (int j = 0; j < 4; ++j) {
            const int gc = n0 + wn + j * 16 + c;
#pragma unroll
            for (int r = 0; r < 4; ++r) {
                const int gr = m0 + wm + i * 16 + g * 4 + r;
                float v = acc[i][j][r];
                if (addmat)
                    v += bf2f(addmat[(size_t)gr * N + gc]) + bf2f(bias[gc]);
                const size_t idx = ooff + (size_t)gr * N + gc;
                if (f32o) ((float*)C)[idx] = v;
                else      ((ushort_t*)C)[idx] = f2bf(v);
            }
        }
    }
}

__global__ __launch_bounds__(256) void gemm_proj(
    const ushort_t* __restrict__ ActC, const ushort_t* __restrict__ WT,
    ushort_t* __restrict__ Pbuf)
{
    const int z = blockIdx.z;
    const int asel = (z == 0) ? 0 : (z <= 2 ? 1 : 2);
    // WT order: 0 Wq, 1 Wk_ta, 2 Wk_tv, 3 Wv_ta, 4 Wv_tv, 5 Wout
    const int wsel = (z == 2) ? 3 : ((z == 3) ? 2 : z);
    gemm_core(ActC + (size_t)asel * 2 * 1024 * 1024,
              WT + (size_t)wsel * 1024 * 1024,
              Pbuf + (size_t)z * 2 * 1024 * 1024, 0, false, nullptr, nullptr);
}

__global__ __launch_bounds__(256) void gemm_out(
    const ushort_t* __restrict__ OutSum, const ushort_t* __restrict__ WoutT,
    const ushort_t* __restrict__ hyperC, const ushort_t* __restrict__ boutC,
    void* __restrict__ out, long ooff, const int* __restrict__ flag)
{
    gemm_core(OutSum, WoutT, out, (size_t)ooff, (*flag != 0), hyperC, boutC);
}

// ---------------------------------------------------------------------------
// Fused dual-stream MFMA flash attention, round-8:
//  - both streams (ta/tv) in one kt loop, 2 barriers per fused tile
//  - register prefetch of next K/V tiles (T14)
//  - Q fragments hoisted to registers (pre-scaled), staged once via Ks[0]
//  - Ks/Ps stride 72; V granule XOR swizzle (conflict-free gather, R2-proven)
//  - NEW: gather addresses hoisted — 4 lane-dependent bases vb[dt], all other
//    terms compile-time immediates -> ds_read_u16 with offset:, zero per-read
//    VALU (R2 showed VALUBusy 33% dominated by gather addressing)
//  - blockIdx: x=head, y=q-tile (XCD locality: id%8==h%8)
// ---------------------------------------------------------------------------
__global__ __launch_bounds__(256) void attn_fused(
    const ushort_t* __restrict__ Qb,
    const ushort_t* __restrict__ Kta, const ushort_t* __restrict__ Vta,
    const ushort_t* __restrict__ Ktv, const ushort_t* __restrict__ Vtv,
    ushort_t* __restrict__ Osum)
{
    const int h = blockIdx.x, qb = blockIdx.y, lb = blockIdx.z;
    const int tid = threadIdx.x, w = tid >> 6, lane = tid & 63;
    const int g = lane >> 4, c = lane & 15;

    __shared__ __align__(16) ushort_t Ks[2][64 * 72];   // K tiles [j][d] pad72
    __shared__ __align__(16) ushort_t Vs[2][64 * 64];   // V tiles, granule-swz
    __shared__ __align__(16) ushort_t Ps[2][4][16 * 72];// per-stream per-wave P

    const float qscale = 0.125f * 1.44269504f;  // SCALE * log2(e)
    const size_t hcol = (size_t)h * 64;
    const size_t kbase = (size_t)lb * 1024;

    // staging coords: row sj (0..31 per half), 8 contiguous cols at sd
    const int sj = tid >> 3;
    const int sd = (tid & 7) * 8;

    const ushort_t* Kp[2] = { Kta, Ktv };
    const ushort_t* Vv[2] = { Vta, Vtv };

    // ---- prefetch kt=0 tiles into registers (in flight during Q setup)
    u32x4 pk[2][2], pv[2][2];
#pragma unroll
    for (int s = 0; s < 2; ++s)
#pragma unroll
        for (int r = 0; r < 2; ++r) {
            const size_t row = kbase + r * 32 + sj;
            pk[s][r] = *(const u32x4*)(Kp[s] + row * 1024 + hcol + sd);
            pv[s][r] = *(const u32x4*)(Vv[s] + row * 1024 + hcol + sd);
        }

    // ---- stage Q through Ks[0]; hoist pre-scaled fragments to registers
    bf16x8 aq[2];
    {
        const size_t qrow0 = kbase + qb * 64;
#pragma unroll
        for (int r = 0; r < 2; ++r)
            *(u32x4*)&Ks[0][(r * 32 + sj) * 72 + sd] =
                *(const u32x4*)(Qb + (qrow0 + r * 32 + sj) * 1024 + hcol + sd);
        __syncthreads();
#pragma unroll
        for (int dh = 0; dh < 2; ++dh) {
            u16x8 raw = *(const u16x8*)&Ks[0][(w * 16 + c) * 72 + dh * 32 + g * 8];
            u16x8 sc;
#pragma unroll
            for (int e = 0; e < 8; ++e) sc[e] = f2bf(bf2f(raw[e]) * qscale);
            aq[dh] = __builtin_bit_cast(bf16x8_b, (u16x8_b)sc);
        }
    }

    floatx4 O[2][4];
    float m[2][4], l[2][4];
#pragma unroll
    for (int s = 0; s < 2; ++s) {
#pragma unroll
        for (int dt = 0; dt < 4; ++dt) O[s][dt] = (floatx4)0.0f;
#pragma unroll
        for (int r = 0; r < 4; ++r) { m[s][r] = -1e30f; l[s][r] = 0.0f; }
    }

    // hoisted V-gather lane bases: elem = s*4096 + jh*2048 + jj*64 + vb[dt]
    // (immediates) where vb[dt] = g*512 + ((dt+g)&3)*16 + c
    const ushort_t* VsF = &Vs[0][0];
    int vb[4];
#pragma unroll
    for (int dt = 0; dt < 4; ++dt)
        vb[dt] = g * 512 + (((dt + g) & 3) << 4) + c;

    for (int kt = 0; kt < 16; ++kt) {
        __syncthreads();  // previous tile's LDS reads complete
        // write staged tiles (compiler inserts vmcnt wait for pk/pv)
#pragma unroll
        for (int s = 0; s < 2; ++s)
#pragma unroll
            for (int r = 0; r < 2; ++r) {
                const int j = r * 32 + sj;
                *(u32x4*)&Ks[s][j * 72 + sd] = pk[s][r];
                // granule swizzle: logical granule sd>>4 -> (sd>>4 + (j>>3))&3
                *(u32x4*)&Vs[s][j * 64 + ((((sd >> 4) + (j >> 3)) & 3) << 4)
                                + (sd & 8)] = pv[s][r];
            }
        // issue next tile's global loads; land during this tile's compute
        if (kt < 15) {
            const size_t krow0 = kbase + (size_t)(kt + 1) * 64;
#pragma unroll
            for (int s = 0; s < 2; ++s)
#pragma unroll
                for (int r = 0; r < 2; ++r) {
                    const size_t row = krow0 + r * 32 + sj;
                    pk[s][r] = *(const u32x4*)(Kp[s] + row * 1024 + hcol + sd);
                    pv[s][r] = *(const u32x4*)(Vv[s] + row * 1024 + hcol + sd);
                }
        }
        __syncthreads();  // tiles visible to all waves

        // ---- QK^T, both streams
        floatx4 S[2][4];
#pragma unroll
        for (int s = 0; s < 2; ++s)
#pragma unroll
            for (int jt = 0; jt < 4; ++jt) S[s][jt] = (floatx4)0.0f;
        __builtin_amdgcn_s_setprio(1);
#pragma unroll
        for (int s = 0; s < 2; ++s)
#pragma unroll
            for (int dh = 0; dh < 2; ++dh)
#pragma unroll
                for (int jt = 0; jt < 4; ++jt) {
                    bf16x8 bk = *(const bf16x8*)&Ks[s][(jt * 16 + c) * 72 + dh * 32 + g * 8];
                    S[s][jt] = __builtin_amdgcn_mfma_f32_16x16x32_bf16(
                        aq[dh], bk, S[s][jt], 0, 0, 0);
                }
        __builtin_amdgcn_s_setprio(0);

        // ---- online softmax + P store + O rescale, per stream
#pragma unroll
        for (int s = 0; s < 2; ++s) {
#pragma unroll
            for (int r = 0; r < 4; ++r) {
                float mx = fmaxf(fmaxf(S[s][0][r], S[s][1][r]), fmaxf(S[s][2][r], S[s][3][r]));
                mx = fmaxf(mx, __shfl_xor(mx, 1));
                mx = fmaxf(mx, __shfl_xor(mx, 2));
                mx = fmaxf(mx, __shfl_xor(mx, 4));
                mx = fmaxf(mx, __shfl_xor(mx, 8));
                const float mn = fmaxf(m[s][r], mx);
                const float al = __builtin_amdgcn_exp2f(m[s][r] - mn);
                m[s][r] = mn;
                float rs = 0.0f;
#pragma unroll
                for (int jt = 0; jt < 4; ++jt) {
                    const float p = __builtin_amdgcn_exp2f(S[s][jt][r] - mn);
                    Ps[s][w][(g * 4 + r) * 72 + jt * 16 + c] = f2bf(p);
                    rs += p;
                }
                rs += __shfl_xor(rs, 1); rs += __shfl_xor(rs, 2);
                rs += __shfl_xor(rs, 4); rs += __shfl_xor(rs, 8);
                l[s][r] = l[s][r] * al + rs;
#pragma unroll
                for (int dt = 0; dt < 4; ++dt) O[s][dt][r] *= al;
            }
        }

        // ---- PV, both streams. Ps is per-wave (same-wave DS ordering):
        //      no barrier needed between Ps write and read.
#pragma unroll
        for (int s = 0; s < 2; ++s) {
#pragma unroll
            for (int jh = 0; jh < 2; ++jh) {
                bf16x8 ap = *(const bf16x8*)&Ps[s][w][c * 72 + jh * 32 + g * 8];
                u16x8 bvu[4];
#pragma unroll
                for (int dt = 0; dt < 4; ++dt) {
#pragma unroll
                    for (int jj = 0; jj < 8; ++jj) {
                        // elem = imm(s,jh,jj) + vb[dt]  -> ds_read_u16 offset:
                        bvu[dt][jj] = VsF[s * 4096 + jh * 2048 + jj * 64 + vb[dt]];
                    }
                }
                __builtin_amdgcn_s_setprio(1);
#pragma unroll
                for (int dt = 0; dt < 4; ++dt) {
                    bf16x8 bv = __builtin_bit_cast(bf16x8_b, (u16x8_b)bvu[dt]);
                    O[s][dt] = __builtin_amdgcn_mfma_f32_16x16x32_bf16(
                        ap, bv, O[s][dt], 0, 0, 0);
                }
                __builtin_amdgcn_s_setprio(0);
            }
        }
    }

    // ---- epilogue: Osum = O_ta/l_ta + O_tv/l_tv
    const size_t orow0 = kbase + qb * 64 + w * 16;
#pragma unroll
    for (int dt = 0; dt < 4; ++dt)
#pragma unroll
        for (int r = 0; r < 4; ++r) {
            const float v = O[0][dt][r] / l[0][r] + O[1][dt][r] / l[1][r];
            Osum[(orow0 + g * 4 + r) * 1024 + hcol + dt * 16 + c] = f2bf(v);
        }
}

// ---------------------------------------------------------------------------
extern "C" void kernel_launch(void* const* d_in, const int* in_sizes, int n_in,
                              void* d_out, int out_size, void* d_ws, size_t ws_size,
                              hipStream_t stream)
{
    const void* h_t     = d_in[0];
    const void* h_a     = d_in[1];
    const void* h_v     = d_in[2];
    const void* h_hyper = d_in[3];
    const void* Wq      = d_in[4];
    const void* Wk_ta   = d_in[5];
    const void* Wk_tv   = d_in[6];
    const void* Wv_ta   = d_in[7];
    const void* Wv_tv   = d_in[8];
    const void* Wout    = d_in[9];
    const void* bout    = d_in[10];

    constexpr size_t MEG = (size_t)1024 * 1024;
    int*      flag  = (int*)d_ws;
    ushort_t* WT    = (ushort_t*)d_ws + 64;
    ushort_t* ActC  = WT + 6 * MEG;
    ushort_t* Pbuf  = ActC + 8 * MEG;
    ushort_t* OSg   = Pbuf + 10 * MEG;
    ushort_t* boutC = OSg + 2 * MEG;

    detect_dtype<<<1, 256, 0, stream>>>((const unsigned int*)h_t, flag);
    conv_weights<<<dim3(16, 16, 6), 256, 0, stream>>>(
        Wq, Wk_ta, Wk_tv, Wv_ta, Wv_tv, Wout, WT, flag);
    conv_bout<<<1, 256, 0, stream>>>(bout, boutC, flag);

    const long GSTRIDE = 2 * 1024 * 1024;
    for (int grp = 0; grp < 4; ++grp) {
        const long off = (long)grp * GSTRIDE;
        conv_act<<<dim3(1024, 4), 256, 0, stream>>>(
            h_t, h_a, h_v, h_hyper, off, ActC, flag);
        gemm_proj<<<dim3(8, 16, 5), 256, 0, stream>>>(ActC, WT, Pbuf);
        attn_fused<<<dim3(16, 16, 2), 256, 0, stream>>>(
            Pbuf,
            Pbuf + 1 * (size_t)GSTRIDE, Pbuf + 2 * (size_t)GSTRIDE,
            Pbuf + 3 * (size_t)GSTRIDE, Pbuf + 4 * (size_t)GSTRIDE,
            OSg);
        gemm_out<<<dim3(8, 16), 256, 0, stream>>>(
            OSg, WT + 5 * MEG, ActC + 6 * MEG, boutC,
            d_out, off, flag);
    }
}

// Round 4
// 639.918 us; speedup vs baseline: 1.5241x; 1.2250x over previous
//
#include <hip/hip_runtime.h>

typedef unsigned short ushort_t;
typedef __bf16 bf16_t;
typedef __bf16 bf16x8_b __attribute__((ext_vector_type(8)));
typedef bf16x8_b __attribute__((may_alias)) bf16x8;
typedef unsigned short u16x8_b __attribute__((ext_vector_type(8)));
typedef u16x8_b __attribute__((may_alias)) u16x8;
typedef unsigned int u32x4_b __attribute__((ext_vector_type(4)));
typedef u32x4_b __attribute__((may_alias)) u32x4;
typedef float floatx4 __attribute__((ext_vector_type(4)));

__device__ __forceinline__ float bf2f(ushort_t h) {
    union { unsigned int u; float f; } v; v.u = ((unsigned int)h) << 16; return v.f;
}
__device__ __forceinline__ ushort_t f2bf(float f) {
    union { float f; unsigned int u; } v; v.f = f;
    unsigned int u = v.u;
    unsigned int r = (u + 0x7FFFu + ((u >> 16) & 1u)) >> 16;
    return (ushort_t)r;
}

// Async global->LDS DMA, 16B per lane. Dest must be wave-uniform base; HW adds
// lane*16. Completion tracked by vmcnt; __syncthreads() drains it.
__device__ __forceinline__ void glds16(const ushort_t* g, ushort_t* l) {
    __builtin_amdgcn_global_load_lds(
        (const __attribute__((address_space(1))) unsigned int*)g,
        (__attribute__((address_space(3))) unsigned int*)l, 16, 0, 0);
}

// ---------------------------------------------------------------------------
// Input dtype sniff: flag=1 means fp32 inputs.
// ---------------------------------------------------------------------------
__global__ __launch_bounds__(256) void detect_dtype(
    const unsigned int* __restrict__ x, int* __restrict__ flag)
{
    __shared__ int cnt;
    if (threadIdx.x == 0) cnt = 0;
    __syncthreads();
    int c = 0;
    for (int i = threadIdx.x; i < 512; i += 256) {
        unsigned int w = x[i];
        unsigned int e = (w >> 7) & 0xFFu;
        if (e >= 0x70u && e <= 0x8Fu) ++c;
    }
    atomicAdd(&cnt, c);
    __syncthreads();
    if (threadIdx.x == 0) *flag = (cnt < 256) ? 1 : 0;
}

// ---------------------------------------------------------------------------
// Transpose+convert 6 weights [1024,1024] -> WT[z][n][k] = bf16(W[k][n])
// ---------------------------------------------------------------------------
__global__ __launch_bounds__(256) void conv_weights(
    const void* __restrict__ w0, const void* __restrict__ w1,
    const void* __restrict__ w2, const void* __restrict__ w3,
    const void* __restrict__ w4, const void* __restrict__ w5,
    ushort_t* __restrict__ WT, const int* __restrict__ flag)
{
    __shared__ ushort_t t[64][65];
    const int z = blockIdx.z;
    const void* src = (z == 0) ? w0 : (z == 1) ? w1 : (z == 2) ? w2
                    : (z == 3) ? w3 : (z == 4) ? w4 : w5;
    const bool isf = (*flag != 0);
    ushort_t* dst = WT + (size_t)z * 1024 * 1024;
    const int x0 = blockIdx.x * 64, y0 = blockIdx.y * 64;
    const int tx = threadIdx.x & 63, ty0 = threadIdx.x >> 6;
#pragma unroll
    for (int r = 0; r < 16; ++r) {
        int ty = ty0 * 16 + r;
        size_t idx = (size_t)(y0 + ty) * 1024 + x0 + tx;
        t[ty][tx] = isf ? f2bf(((const float*)src)[idx]) : ((const ushort_t*)src)[idx];
    }
    __syncthreads();
#pragma unroll
    for (int r = 0; r < 16; ++r) {
        int ty = ty0 * 16 + r;
        dst[(size_t)(x0 + ty) * 1024 + y0 + tx] = t[tx][ty];
    }
}

__global__ __launch_bounds__(256) void conv_bout(
    const void* __restrict__ bout, ushort_t* __restrict__ dst,
    const int* __restrict__ flag)
{
    const bool isf = (*flag != 0);
    for (int i = threadIdx.x; i < 1024; i += 256)
        dst[i] = isf ? f2bf(((const float*)bout)[i]) : ((const ushort_t*)bout)[i];
}

// ---------------------------------------------------------------------------
// Convert a slice of {h_t,h_a,h_v} to bf16 in ws (h_hyper no longer staged:
// gemm_out reads it raw as the residual addend).
// ---------------------------------------------------------------------------
__global__ __launch_bounds__(256) void conv_act(
    const void* __restrict__ h_t, const void* __restrict__ h_a,
    const void* __restrict__ h_v,
    long off, ushort_t* __restrict__ ActC, long tstride,
    const int* __restrict__ flag)
{
    const int z = blockIdx.y;
    const void* s = (z == 0) ? h_t : (z == 1) ? h_a : h_v;
    const size_t e8 = ((size_t)blockIdx.x * 256 + threadIdx.x) * 8;
    ushort_t* dst = ActC + (size_t)z * tstride + e8;
    if (*flag) {
        const float* f = (const float*)s + off + e8;
        u32x4 o;
#pragma unroll
        for (int j = 0; j < 4; ++j) {
            unsigned int lo = f2bf(f[2 * j]);
            unsigned int hi = f2bf(f[2 * j + 1]);
            o[j] = lo | (hi << 16);
        }
        *(u32x4*)dst = o;
    } else {
        const ushort_t* b = (const ushort_t*)s + off + e8;
        *(u32x4*)dst = *(const u32x4*)b;
    }
}

// ---------------------------------------------------------------------------
// Core GEMM: C[M,1024] = A[M,1024] @ B, BT[1024,1024] given. Tile 128x128.
// Staging via global_load_lds width=16. addraw (optional residual) is read in
// its native dtype (isf) at f32 precision.
// ---------------------------------------------------------------------------
__device__ __forceinline__ void gemm_core(
    const ushort_t* __restrict__ A, const ushort_t* __restrict__ BT,
    void* __restrict__ C, size_t ooff, bool f32o,
    const void* __restrict__ addraw, long aoff,
    const ushort_t* __restrict__ bias, bool isf)
{
    constexpr int K = 1024, N = 1024;
    __shared__ __align__(16) ushort_t As[128 * 32];  // [m][k] linear
    __shared__ __align__(16) ushort_t Bs[128 * 32];  // [n][k] linear
    const int tid = threadIdx.x;
    const int w = tid >> 6, lane = tid & 63;
    const int g = lane >> 4, c = lane & 15;
    const int m0 = blockIdx.y * 128, n0 = blockIdx.x * 128;
    const int wm = (w >> 1) * 64, wn = (w & 1) * 64;

    const int srow = w * 32 + (lane >> 2);
    const int scol = (lane & 3) * 8;
    const ushort_t* Ag = A + (size_t)(m0 + srow) * K + scol;
    const ushort_t* Bg = BT + (size_t)(n0 + srow) * K + scol;
    ushort_t* AsW = &As[w * 1024];
    ushort_t* BsW = &Bs[w * 1024];

    floatx4 acc[4][4];
#pragma unroll
    for (int i = 0; i < 4; ++i)
#pragma unroll
        for (int j = 0; j < 4; ++j) acc[i][j] = (floatx4)0.0f;

    for (int k0 = 0; k0 < K; k0 += 32) {
        __syncthreads();
        glds16(Ag + k0,          AsW);
        glds16(Ag + k0 + 16 * K, AsW + 512);
        glds16(Bg + k0,          BsW);
        glds16(Bg + k0 + 16 * K, BsW + 512);
        __syncthreads();
        bf16x8 af[4], bfr[4];
#pragma unroll
        for (int i = 0; i < 4; ++i)
            af[i] = *(const bf16x8*)&As[(wm + i * 16 + c) * 32 + g * 8];
#pragma unroll
        for (int j = 0; j < 4; ++j)
            bfr[j] = *(const bf16x8*)&Bs[(wn + j * 16 + c) * 32 + g * 8];
#pragma unroll
        for (int i = 0; i < 4; ++i)
#pragma unroll
            for (int j = 0; j < 4; ++j)
                acc[i][j] = __builtin_amdgcn_mfma_f32_16x16x32_bf16(
                    af[i], bfr[j], acc[i][j], 0, 0, 0);
    }
#pragma unroll
    for (int i = 0; i < 4; ++i) {
#pragma unroll
        for (int j = 0; j < 4; ++j) {
            const int gc = n0 + wn + j * 16 + c;
#pragma unroll
            for (int r = 0; r < 4; ++r) {
                const int gr = m0 + wm + i * 16 + g * 4 + r;
                float v = acc[i][j][r];
                if (addraw) {
                    const size_t ai = (size_t)aoff + (size_t)gr * N + gc;
                    const float av = isf ? ((const float*)addraw)[ai]
                                         : bf2f(((const ushort_t*)addraw)[ai]);
                    v += av + bf2f(bias[gc]);
                }
                const size_t idx = ooff + (size_t)gr * N + gc;
                if (f32o) ((float*)C)[idx] = v;
                else      ((ushort_t*)C)[idx] = f2bf(v);
            }
        }
    }
}

__global__ __launch_bounds__(256) void gemm_proj(
    const ushort_t* __restrict__ ActC, const ushort_t* __restrict__ WT,
    ushort_t* __restrict__ Pbuf, long astride, long pstride)
{
    const int z = blockIdx.z;
    const int asel = (z == 0) ? 0 : (z <= 2 ? 1 : 2);
    // WT order: 0 Wq, 1 Wk_ta, 2 Wk_tv, 3 Wv_ta, 4 Wv_tv, 5 Wout
    const int wsel = (z == 2) ? 3 : ((z == 3) ? 2 : z);
    gemm_core(ActC + (size_t)asel * astride,
              WT + (size_t)wsel * 1024 * 1024,
              Pbuf + (size_t)z * pstride, 0, false,
              nullptr, 0, nullptr, false);
}

__global__ __launch_bounds__(256) void gemm_out(
    const ushort_t* __restrict__ OutSum, const ushort_t* __restrict__ WoutT,
    const void* __restrict__ hyper_raw, long aoff,
    const ushort_t* __restrict__ boutC,
    void* __restrict__ out, long ooff, const int* __restrict__ flag)
{
    const bool isf = (*flag != 0);
    gemm_core(OutSum, WoutT, out, (size_t)ooff, isf,
              hyper_raw, aoff, boutC, isf);
}

// ---------------------------------------------------------------------------
// Fused dual-stream MFMA flash attention, round-9:
//  - 512-thread blocks, 128-row q-tiles (8 waves x 16 rows): staging/barrier
//    cost amortized 2x, K/V HBM re-fetch halved vs 64-row tiles
//  - Ps reused across the two streams (softmax(s)+PV(s) sequential within the
//    wave; same-wave DS ordering, no barrier) -> LDS stays 53248B
//  - register prefetch of next K/V tiles; V granule XOR swizzle (R2-proven)
//  - blockIdx: x=head (XCD locality: id%8==h%8)
// ---------------------------------------------------------------------------
__global__ __launch_bounds__(512) void attn_fused(
    const ushort_t* __restrict__ Qb,
    const ushort_t* __restrict__ Kta, const ushort_t* __restrict__ Vta,
    const ushort_t* __restrict__ Ktv, const ushort_t* __restrict__ Vtv,
    ushort_t* __restrict__ Osum)
{
    const int h = blockIdx.x, qb = blockIdx.y, lb = blockIdx.z;
    const int tid = threadIdx.x, w = tid >> 6, lane = tid & 63;
    const int g = lane >> 4, c = lane & 15;

    __shared__ __align__(16) ushort_t Ks[2][64 * 72];   // K tiles [j][d] pad72
    __shared__ __align__(16) ushort_t Vs[2][64 * 64];   // V tiles, granule-swz
    __shared__ __align__(16) ushort_t Ps[8][16 * 72];   // per-wave P (s-shared)

    const float qscale = 0.125f * 1.44269504f;  // SCALE * log2(e)
    const size_t hcol = (size_t)h * 64;
    const size_t kbase = (size_t)lb * 1024;

    // staging coords: 512 threads cover 64 rows x 64 cols in one shot
    const int sj = tid >> 3;            // 0..63
    const int sd = (tid & 7) * 8;       // 0..56

    const ushort_t* Kp[2] = { Kta, Ktv };
    const ushort_t* Vv[2] = { Vta, Vtv };

    // ---- prefetch kt=0 tiles into registers (in flight during Q setup)
    u32x4 pk[2], pv[2];
#pragma unroll
    for (int s = 0; s < 2; ++s) {
        const size_t row = kbase + sj;
        pk[s] = *(const u32x4*)(Kp[s] + row * 1024 + hcol + sd);
        pv[s] = *(const u32x4*)(Vv[s] + row * 1024 + hcol + sd);
    }

    // ---- stage Q (128 rows) through Ks[0..1]; hoist pre-scaled fragments
    bf16x8 aq[2];
    {
        const size_t qrow0 = kbase + (size_t)qb * 128;
#pragma unroll
        for (int r = 0; r < 2; ++r)
            *(u32x4*)&Ks[r][sj * 72 + sd] =
                *(const u32x4*)(Qb + (qrow0 + r * 64 + sj) * 1024 + hcol + sd);
        __syncthreads();
        const int qbuf = w >> 2, qrow = (w & 3) * 16;
#pragma unroll
        for (int dh = 0; dh < 2; ++dh) {
            u16x8 raw = *(const u16x8*)&Ks[qbuf][(qrow + c) * 72 + dh * 32 + g * 8];
            u16x8 sc;
#pragma unroll
            for (int e = 0; e < 8; ++e) sc[e] = f2bf(bf2f(raw[e]) * qscale);
            aq[dh] = __builtin_bit_cast(bf16x8_b, (u16x8_b)sc);
        }
    }

    floatx4 O[2][4];
    float m[2][4], l[2][4];
#pragma unroll
    for (int s = 0; s < 2; ++s) {
#pragma unroll
        for (int dt = 0; dt < 4; ++dt) O[s][dt] = (floatx4)0.0f;
#pragma unroll
        for (int r = 0; r < 4; ++r) { m[s][r] = -1e30f; l[s][r] = 0.0f; }
    }

    // V-gather lane bases: elem = s*4096 + jh*2048 + jj*64 + vb[dt]
    const ushort_t* VsF = &Vs[0][0];
    int vb[4];
#pragma unroll
    for (int dt = 0; dt < 4; ++dt)
        vb[dt] = g * 512 + (((dt + g) & 3) << 4) + c;

    for (int kt = 0; kt < 16; ++kt) {
        __syncthreads();  // previous tile's LDS reads complete
#pragma unroll
        for (int s = 0; s < 2; ++s) {
            *(u32x4*)&Ks[s][sj * 72 + sd] = pk[s];
            // granule swizzle: logical granule sd>>4 -> (sd>>4 + (sj>>3))&3
            *(u32x4*)&Vs[s][sj * 64 + ((((sd >> 4) + (sj >> 3)) & 3) << 4)
                            + (sd & 8)] = pv[s];
        }
        if (kt < 15) {
            const size_t krow0 = kbase + (size_t)(kt + 1) * 64;
#pragma unroll
            for (int s = 0; s < 2; ++s) {
                const size_t row = krow0 + sj;
                pk[s] = *(const u32x4*)(Kp[s] + row * 1024 + hcol + sd);
                pv[s] = *(const u32x4*)(Vv[s] + row * 1024 + hcol + sd);
            }
        }
        __syncthreads();  // tiles visible to all waves

        // ---- QK^T, both streams
        floatx4 S[2][4];
#pragma unroll
        for (int s = 0; s < 2; ++s)
#pragma unroll
            for (int jt = 0; jt < 4; ++jt) S[s][jt] = (floatx4)0.0f;
        __builtin_amdgcn_s_setprio(1);
#pragma unroll
        for (int s = 0; s < 2; ++s)
#pragma unroll
            for (int dh = 0; dh < 2; ++dh)
#pragma unroll
                for (int jt = 0; jt < 4; ++jt) {
                    bf16x8 bk = *(const bf16x8*)&Ks[s][(jt * 16 + c) * 72 + dh * 32 + g * 8];
                    S[s][jt] = __builtin_amdgcn_mfma_f32_16x16x32_bf16(
                        aq[dh], bk, S[s][jt], 0, 0, 0);
                }
        __builtin_amdgcn_s_setprio(0);

        // ---- per stream: online softmax -> Ps -> PV  (Ps reused across s;
        //      same-wave DS ordering makes that safe without barriers)
#pragma unroll
        for (int s = 0; s < 2; ++s) {
#pragma unroll
            for (int r = 0; r < 4; ++r) {
                float mx = fmaxf(fmaxf(S[s][0][r], S[s][1][r]), fmaxf(S[s][2][r], S[s][3][r]));
                mx = fmaxf(mx, __shfl_xor(mx, 1));
                mx = fmaxf(mx, __shfl_xor(mx, 2));
                mx = fmaxf(mx, __shfl_xor(mx, 4));
                mx = fmaxf(mx, __shfl_xor(mx, 8));
                const float mn = fmaxf(m[s][r], mx);
                const float al = __builtin_amdgcn_exp2f(m[s][r] - mn);
                m[s][r] = mn;
                float rs = 0.0f;
#pragma unroll
                for (int jt = 0; jt < 4; ++jt) {
                    const float p = __builtin_amdgcn_exp2f(S[s][jt][r] - mn);
                    Ps[w][(g * 4 + r) * 72 + jt * 16 + c] = f2bf(p);
                    rs += p;
                }
                rs += __shfl_xor(rs, 1); rs += __shfl_xor(rs, 2);
                rs += __shfl_xor(rs, 4); rs += __shfl_xor(rs, 8);
                l[s][r] = l[s][r] * al + rs;
#pragma unroll
                for (int dt = 0; dt < 4; ++dt) O[s][dt][r] *= al;
            }

#pragma unroll
            for (int jh = 0; jh < 2; ++jh) {
                bf16x8 ap = *(const bf16x8*)&Ps[w][c * 72 + jh * 32 + g * 8];
                u16x8 bvu[4];
#pragma unroll
                for (int dt = 0; dt < 4; ++dt) {
#pragma unroll
                    for (int jj = 0; jj < 8; ++jj)
                        bvu[dt][jj] = VsF[s * 4096 + jh * 2048 + jj * 64 + vb[dt]];
                }
                __builtin_amdgcn_s_setprio(1);
#pragma unroll
                for (int dt = 0; dt < 4; ++dt) {
                    bf16x8 bv = __builtin_bit_cast(bf16x8_b, (u16x8_b)bvu[dt]);
                    O[s][dt] = __builtin_amdgcn_mfma_f32_16x16x32_bf16(
                        ap, bv, O[s][dt], 0, 0, 0);
                }
                __builtin_amdgcn_s_setprio(0);
            }
        }
    }

    // ---- epilogue: Osum = O_ta/l_ta + O_tv/l_tv
    const size_t orow0 = kbase + (size_t)qb * 128 + w * 16;
#pragma unroll
    for (int dt = 0; dt < 4; ++dt)
#pragma unroll
        for (int r = 0; r < 4; ++r) {
            const float v = O[0][dt][r] / l[0][r] + O[1][dt][r] / l[1][r];
            Osum[(orow0 + g * 4 + r) * 1024 + hcol + dt * 16 + c] = f2bf(v);
        }
}

// ---------------------------------------------------------------------------
extern "C" void kernel_launch(void* const* d_in, const int* in_sizes, int n_in,
                              void* d_out, int out_size, void* d_ws, size_t ws_size,
                              hipStream_t stream)
{
    const void* h_t     = d_in[0];
    const void* h_a     = d_in[1];
    const void* h_v     = d_in[2];
    const void* h_hyper = d_in[3];
    const void* Wq      = d_in[4];
    const void* Wk_ta   = d_in[5];
    const void* Wk_tv   = d_in[6];
    const void* Wv_ta   = d_in[7];
    const void* Wv_tv   = d_in[8];
    const void* Wout    = d_in[9];
    const void* bout    = d_in[10];

    constexpr size_t MEG = (size_t)1024 * 1024;
    // header: flag at elem 0, boutC at elem 1024; payload starts at elem 4096
    int*      flag  = (int*)d_ws;
    ushort_t* boutC = (ushort_t*)d_ws + 1024;
    ushort_t* WT    = (ushort_t*)d_ws + 4096;

    detect_dtype<<<1, 256, 0, stream>>>((const unsigned int*)h_t, flag);
    conv_weights<<<dim3(16, 16, 6), 256, 0, stream>>>(
        Wq, Wk_ta, Wk_tv, Wv_ta, Wv_tv, Wout, WT, flag);
    conv_bout<<<1, 256, 0, stream>>>(bout, boutC, flag);

    // merged path needs: 4096 + 6M(WT) + 24M(ActC) + 40M(Pbuf) elements
    const size_t need_merged = (4096 + 70 * MEG) * sizeof(ushort_t);

    if (ws_size >= need_merged) {
        // ---- single pass over all 8 batches ----
        ushort_t* ActC = WT + 6 * MEG;          // 3 x 8M (h_t,h_a,h_v bf16)
        ushort_t* Pbuf = ActC + 24 * MEG;       // 5 x 8M projections
        ushort_t* OSg  = ActC;                  // alias: ActC dead after proj

        conv_act<<<dim3(4096, 3), 256, 0, stream>>>(
            h_t, h_a, h_v, 0, ActC, (long)(8 * MEG), flag);
        gemm_proj<<<dim3(8, 64, 5), 256, 0, stream>>>(
            ActC, WT, Pbuf, (long)(8 * MEG), (long)(8 * MEG));
        attn_fused<<<dim3(16, 8, 8), 512, 0, stream>>>(
            Pbuf,
            Pbuf + 8 * MEG,  Pbuf + 16 * MEG,
            Pbuf + 24 * MEG, Pbuf + 32 * MEG,
            OSg);
        gemm_out<<<dim3(8, 64), 256, 0, stream>>>(
            OSg, WT + 5 * MEG, h_hyper, 0, boutC, d_out, 0, flag);
    } else {
        // ---- fallback: 4 groups of 2 batches (proven path geometry) ----
        ushort_t* ActC = WT + 6 * MEG;          // 3 x 2M
        ushort_t* Pbuf = ActC + 6 * MEG;        // 5 x 2M
        ushort_t* OSg  = ActC;                  // alias: ActC dead after proj
        const long GSTRIDE = 2 * 1024 * 1024;
        for (int grp = 0; grp < 4; ++grp) {
            const long off = (long)grp * GSTRIDE;
            conv_act<<<dim3(1024, 3), 256, 0, stream>>>(
                h_t, h_a, h_v, off, ActC, (long)(2 * MEG), flag);
            gemm_proj<<<dim3(8, 16, 5), 256, 0, stream>>>(
                ActC, WT, Pbuf, (long)(2 * MEG), (long)(2 * MEG));
            attn_fused<<<dim3(16, 8, 2), 512, 0, stream>>>(
                Pbuf,
                Pbuf + 2 * MEG, Pbuf + 4 * MEG,
                Pbuf + 6 * MEG, Pbuf + 8 * MEG,
                OSg);
            gemm_out<<<dim3(8, 16), 256, 0, stream>>>(
                OSg, WT + 5 * MEG, h_hyper, off, boutC, d_out, off, flag);
        }
    }
}

// Round 5
// 603.430 us; speedup vs baseline: 1.6162x; 1.0605x over previous
//
#include <hip/hip_runtime.h>

typedef unsigned short ushort_t;
typedef __bf16 bf16_t;
typedef __bf16 bf16x8_b __attribute__((ext_vector_type(8)));
typedef bf16x8_b __attribute__((may_alias)) bf16x8;
typedef unsigned short u16x8_b __attribute__((ext_vector_type(8)));
typedef u16x8_b __attribute__((may_alias)) u16x8;
typedef unsigned short u16x4_b __attribute__((ext_vector_type(4)));
typedef u16x4_b __attribute__((may_alias)) u16x4;
typedef unsigned int u32x4_b __attribute__((ext_vector_type(4)));
typedef u32x4_b __attribute__((may_alias)) u32x4;
typedef float floatx4 __attribute__((ext_vector_type(4)));

__device__ __forceinline__ float bf2f(ushort_t h) {
    union { unsigned int u; float f; } v; v.u = ((unsigned int)h) << 16; return v.f;
}
__device__ __forceinline__ ushort_t f2bf(float f) {
    union { float f; unsigned int u; } v; v.f = f;
    unsigned int u = v.u;
    unsigned int r = (u + 0x7FFFu + ((u >> 16) & 1u)) >> 16;
    return (ushort_t)r;
}

// Async global->LDS DMA, 16B per lane. Dest must be wave-uniform base; HW adds
// lane*16. Completion tracked by vmcnt; __syncthreads() drains it.
__device__ __forceinline__ void glds16(const ushort_t* g, ushort_t* l) {
    __builtin_amdgcn_global_load_lds(
        (const __attribute__((address_space(1))) unsigned int*)g,
        (__attribute__((address_space(3))) unsigned int*)l, 16, 0, 0);
}

// ---------------------------------------------------------------------------
// Input dtype sniff: flag=1 means fp32 inputs.
// ---------------------------------------------------------------------------
__global__ __launch_bounds__(256) void detect_dtype(
    const unsigned int* __restrict__ x, int* __restrict__ flag)
{
    __shared__ int cnt;
    if (threadIdx.x == 0) cnt = 0;
    __syncthreads();
    int c = 0;
    for (int i = threadIdx.x; i < 512; i += 256) {
        unsigned int w = x[i];
        unsigned int e = (w >> 7) & 0xFFu;
        if (e >= 0x70u && e <= 0x8Fu) ++c;
    }
    atomicAdd(&cnt, c);
    __syncthreads();
    if (threadIdx.x == 0) *flag = (cnt < 256) ? 1 : 0;
}

// ---------------------------------------------------------------------------
// Transpose+convert 6 weights [1024,1024] -> WT[z][n][k] = bf16(W[k][n])
// ---------------------------------------------------------------------------
__global__ __launch_bounds__(256) void conv_weights(
    const void* __restrict__ w0, const void* __restrict__ w1,
    const void* __restrict__ w2, const void* __restrict__ w3,
    const void* __restrict__ w4, const void* __restrict__ w5,
    ushort_t* __restrict__ WT, const int* __restrict__ flag)
{
    __shared__ ushort_t t[64][65];
    const int z = blockIdx.z;
    const void* src = (z == 0) ? w0 : (z == 1) ? w1 : (z == 2) ? w2
                    : (z == 3) ? w3 : (z == 4) ? w4 : w5;
    const bool isf = (*flag != 0);
    ushort_t* dst = WT + (size_t)z * 1024 * 1024;
    const int x0 = blockIdx.x * 64, y0 = blockIdx.y * 64;
    const int tx = threadIdx.x & 63, ty0 = threadIdx.x >> 6;
#pragma unroll
    for (int r = 0; r < 16; ++r) {
        int ty = ty0 * 16 + r;
        size_t idx = (size_t)(y0 + ty) * 1024 + x0 + tx;
        t[ty][tx] = isf ? f2bf(((const float*)src)[idx]) : ((const ushort_t*)src)[idx];
    }
    __syncthreads();
#pragma unroll
    for (int r = 0; r < 16; ++r) {
        int ty = ty0 * 16 + r;
        dst[(size_t)(x0 + ty) * 1024 + y0 + tx] = t[tx][ty];
    }
}

__global__ __launch_bounds__(256) void conv_bout(
    const void* __restrict__ bout, ushort_t* __restrict__ dst,
    const int* __restrict__ flag)
{
    const bool isf = (*flag != 0);
    for (int i = threadIdx.x; i < 1024; i += 256)
        dst[i] = isf ? f2bf(((const float*)bout)[i]) : ((const ushort_t*)bout)[i];
}

// ---------------------------------------------------------------------------
// Convert a slice of {h_t,h_a,h_v} to bf16 in ws (h_hyper read raw later).
// ---------------------------------------------------------------------------
__global__ __launch_bounds__(256) void conv_act(
    const void* __restrict__ h_t, const void* __restrict__ h_a,
    const void* __restrict__ h_v,
    long off, ushort_t* __restrict__ ActC, long tstride,
    const int* __restrict__ flag)
{
    const int z = blockIdx.y;
    const void* s = (z == 0) ? h_t : (z == 1) ? h_a : h_v;
    const size_t e8 = ((size_t)blockIdx.x * 256 + threadIdx.x) * 8;
    ushort_t* dst = ActC + (size_t)z * tstride + e8;
    if (*flag) {
        const float* f = (const float*)s + off + e8;
        u32x4 o;
#pragma unroll
        for (int j = 0; j < 4; ++j) {
            unsigned int lo = f2bf(f[2 * j]);
            unsigned int hi = f2bf(f[2 * j + 1]);
            o[j] = lo | (hi << 16);
        }
        *(u32x4*)dst = o;
    } else {
        const ushort_t* b = (const ushort_t*)s + off + e8;
        *(u32x4*)dst = *(const u32x4*)b;
    }
}

// ---------------------------------------------------------------------------
// Core GEMM: C[M,1024] = A[M,1024] @ B, BT[1024,1024] given. Tile 128x128.
// Staging via global_load_lds width=16. Optional transposed bf16 output
// (tr=true): writes VT[b][gc][n] with b=gr>>10, n=gr&1023 — 8B stores of 4
// consecutive tokens. Used for the V projections so attention's PV step can
// read V^T with vector ds_read_b128 instead of scalar gathers.
// ---------------------------------------------------------------------------
__device__ __forceinline__ void gemm_core(
    const ushort_t* __restrict__ A, const ushort_t* __restrict__ BT,
    void* __restrict__ C, size_t ooff, bool f32o, bool tr,
    const void* __restrict__ addraw, long aoff,
    const ushort_t* __restrict__ bias, bool isf)
{
    constexpr int K = 1024, N = 1024;
    __shared__ __align__(16) ushort_t As[128 * 32];  // [m][k] linear
    __shared__ __align__(16) ushort_t Bs[128 * 32];  // [n][k] linear
    const int tid = threadIdx.x;
    const int w = tid >> 6, lane = tid & 63;
    const int g = lane >> 4, c = lane & 15;
    const int m0 = blockIdx.y * 128, n0 = blockIdx.x * 128;
    const int wm = (w >> 1) * 64, wn = (w & 1) * 64;

    const int srow = w * 32 + (lane >> 2);
    const int scol = (lane & 3) * 8;
    const ushort_t* Ag = A + (size_t)(m0 + srow) * K + scol;
    const ushort_t* Bg = BT + (size_t)(n0 + srow) * K + scol;
    ushort_t* AsW = &As[w * 1024];
    ushort_t* BsW = &Bs[w * 1024];

    floatx4 acc[4][4];
#pragma unroll
    for (int i = 0; i < 4; ++i)
#pragma unroll
        for (int j = 0; j < 4; ++j) acc[i][j] = (floatx4)0.0f;

    for (int k0 = 0; k0 < K; k0 += 32) {
        __syncthreads();
        glds16(Ag + k0,          AsW);
        glds16(Ag + k0 + 16 * K, AsW + 512);
        glds16(Bg + k0,          BsW);
        glds16(Bg + k0 + 16 * K, BsW + 512);
        __syncthreads();
        bf16x8 af[4], bfr[4];
#pragma unroll
        for (int i = 0; i < 4; ++i)
            af[i] = *(const bf16x8*)&As[(wm + i * 16 + c) * 32 + g * 8];
#pragma unroll
        for (int j = 0; j < 4; ++j)
            bfr[j] = *(const bf16x8*)&Bs[(wn + j * 16 + c) * 32 + g * 8];
#pragma unroll
        for (int i = 0; i < 4; ++i)
#pragma unroll
            for (int j = 0; j < 4; ++j)
                acc[i][j] = __builtin_amdgcn_mfma_f32_16x16x32_bf16(
                    af[i], bfr[j], acc[i][j], 0, 0, 0);
    }
#pragma unroll
    for (int i = 0; i < 4; ++i) {
#pragma unroll
        for (int j = 0; j < 4; ++j) {
            const int gc = n0 + wn + j * 16 + c;
            const int gr0 = m0 + wm + i * 16 + g * 4;
            if (tr) {
                // transposed bf16 store: VT[b][gc][n], 4 consecutive n
                u16x4 o4;
#pragma unroll
                for (int r = 0; r < 4; ++r) o4[r] = f2bf(acc[i][j][r]);
                const size_t ti = ((size_t)(gr0 >> 10) << 20)
                                + (size_t)gc * 1024 + (gr0 & 1023);
                *(u16x4*)&((ushort_t*)C)[ti] = o4;
            } else {
#pragma unroll
                for (int r = 0; r < 4; ++r) {
                    const int gr = gr0 + r;
                    float v = acc[i][j][r];
                    if (addraw) {
                        const size_t ai = (size_t)aoff + (size_t)gr * N + gc;
                        const float av = isf ? ((const float*)addraw)[ai]
                                             : bf2f(((const ushort_t*)addraw)[ai]);
                        v += av + bf2f(bias[gc]);
                    }
                    const size_t idx = ooff + (size_t)gr * N + gc;
                    if (f32o) ((float*)C)[idx] = v;
                    else      ((ushort_t*)C)[idx] = f2bf(v);
                }
            }
        }
    }
}

__global__ __launch_bounds__(256) void gemm_proj(
    const ushort_t* __restrict__ ActC, const ushort_t* __restrict__ WT,
    ushort_t* __restrict__ Pbuf, long astride, long pstride)
{
    const int z = blockIdx.z;
    const int asel = (z == 0) ? 0 : (z <= 2 ? 1 : 2);
    // WT order: 0 Wq, 1 Wk_ta, 2 Wk_tv, 3 Wv_ta, 4 Wv_tv, 5 Wout
    const int wsel = (z == 2) ? 3 : ((z == 3) ? 2 : z);
    const bool tr = (z == 2) || (z == 4);   // V projections -> transposed
    gemm_core(ActC + (size_t)asel * astride,
              WT + (size_t)wsel * 1024 * 1024,
              Pbuf + (size_t)z * pstride, 0, false, tr,
              nullptr, 0, nullptr, false);
}

__global__ __launch_bounds__(256) void gemm_out(
    const ushort_t* __restrict__ OutSum, const ushort_t* __restrict__ WoutT,
    const void* __restrict__ hyper_raw, long aoff,
    const ushort_t* __restrict__ boutC,
    void* __restrict__ out, long ooff, const int* __restrict__ flag)
{
    const bool isf = (*flag != 0);
    gemm_core(OutSum, WoutT, out, (size_t)ooff, isf, false,
              hyper_raw, aoff, boutC, isf);
}

// ---------------------------------------------------------------------------
// Fused dual-stream MFMA flash attention, round-10:
//  - V consumed from VT (d-major, produced transposed by gemm_proj): PV
//    B-fragments are vector ds_read_b128 — the 128 scalar gathers/wave-iter
//    of R9 are gone (they were ~half the DS-pipe load; MfmaUtil was 9.6%)
//  - all LDS strides 68 (uniform bank spread; total 52224B -> 3 blocks/CU)
//  - 512-thread blocks, 128-row q-tiles; Ps reused across streams
//  - register prefetch of next K/V tiles
//  - blockIdx: x=head (XCD locality: all qb/lb siblings of h on one XCD)
// ---------------------------------------------------------------------------
__global__ __launch_bounds__(512) void attn_fused(
    const ushort_t* __restrict__ Qb,
    const ushort_t* __restrict__ Kta, const ushort_t* __restrict__ Vta,
    const ushort_t* __restrict__ Ktv, const ushort_t* __restrict__ Vtv,
    ushort_t* __restrict__ Osum)
{
    const int h = blockIdx.x, qb = blockIdx.y, lb = blockIdx.z;
    const int tid = threadIdx.x, w = tid >> 6, lane = tid & 63;
    const int g = lane >> 4, c = lane & 15;

    __shared__ __align__(16) ushort_t Ks[2][64 * 68];   // K tiles [j][d]
    __shared__ __align__(16) ushort_t Vt[2][64 * 68];   // V^T tiles [d][j]
    __shared__ __align__(16) ushort_t Ps[8][16 * 68];   // per-wave P

    const float qscale = 0.125f * 1.44269504f;  // SCALE * log2(e)
    const size_t hcol = (size_t)h * 64;
    const size_t kbase = (size_t)lb * 1024;

    // staging coords: 512 threads cover 64 rows x 64 cols in one shot
    const int sj = tid >> 3;            // 0..63
    const int sd = (tid & 7) * 8;       // 0..56

    const ushort_t* Kp[2] = { Kta, Ktv };
    const ushort_t* Vv[2] = { Vta, Vtv };
    // VT row base for this (lb, h): VT[lb][hcol + sj][*]
    const size_t vrow = (size_t)lb * 1048576 + (hcol + sj) * 1024;

    // ---- prefetch kt=0 tiles into registers (in flight during Q setup)
    u32x4 pk[2], pv[2];
#pragma unroll
    for (int s = 0; s < 2; ++s) {
        pk[s] = *(const u32x4*)(Kp[s] + (kbase + sj) * 1024 + hcol + sd);
        pv[s] = *(const u32x4*)(Vv[s] + vrow + sd);
    }

    // ---- stage Q (128 rows) through Ks[0..1]; hoist pre-scaled fragments
    bf16x8 aq[2];
    {
        const size_t qrow0 = kbase + (size_t)qb * 128;
#pragma unroll
        for (int r = 0; r < 2; ++r)
            *(u32x4*)&Ks[r][sj * 68 + sd] =
                *(const u32x4*)(Qb + (qrow0 + r * 64 + sj) * 1024 + hcol + sd);
        __syncthreads();
        const int qbuf = w >> 2, qrow = (w & 3) * 16;
#pragma unroll
        for (int dh = 0; dh < 2; ++dh) {
            u16x8 raw = *(const u16x8*)&Ks[qbuf][(qrow + c) * 68 + dh * 32 + g * 8];
            u16x8 sc;
#pragma unroll
            for (int e = 0; e < 8; ++e) sc[e] = f2bf(bf2f(raw[e]) * qscale);
            aq[dh] = __builtin_bit_cast(bf16x8_b, (u16x8_b)sc);
        }
    }

    floatx4 O[2][4];
    float m[2][4], l[2][4];
#pragma unroll
    for (int s = 0; s < 2; ++s) {
#pragma unroll
        for (int dt = 0; dt < 4; ++dt) O[s][dt] = (floatx4)0.0f;
#pragma unroll
        for (int r = 0; r < 4; ++r) { m[s][r] = -1e30f; l[s][r] = 0.0f; }
    }

    for (int kt = 0; kt < 16; ++kt) {
        __syncthreads();  // previous tile's LDS reads complete
#pragma unroll
        for (int s = 0; s < 2; ++s) {
            *(u32x4*)&Ks[s][sj * 68 + sd] = pk[s];
            *(u32x4*)&Vt[s][sj * 68 + sd] = pv[s];
        }
        if (kt < 15) {
            const size_t krow0 = kbase + (size_t)(kt + 1) * 64;
#pragma unroll
            for (int s = 0; s < 2; ++s) {
                pk[s] = *(const u32x4*)(Kp[s] + (krow0 + sj) * 1024 + hcol + sd);
                pv[s] = *(const u32x4*)(Vv[s] + vrow + (kt + 1) * 64 + sd);
            }
        }
        __syncthreads();  // tiles visible to all waves

        // ---- QK^T, both streams
        floatx4 S[2][4];
#pragma unroll
        for (int s = 0; s < 2; ++s)
#pragma unroll
            for (int jt = 0; jt < 4; ++jt) S[s][jt] = (floatx4)0.0f;
        __builtin_amdgcn_s_setprio(1);
#pragma unroll
        for (int s = 0; s < 2; ++s)
#pragma unroll
            for (int dh = 0; dh < 2; ++dh)
#pragma unroll
                for (int jt = 0; jt < 4; ++jt) {
                    bf16x8 bk = *(const bf16x8*)&Ks[s][(jt * 16 + c) * 68 + dh * 32 + g * 8];
                    S[s][jt] = __builtin_amdgcn_mfma_f32_16x16x32_bf16(
                        aq[dh], bk, S[s][jt], 0, 0, 0);
                }
        __builtin_amdgcn_s_setprio(0);

        // ---- per stream: online softmax -> Ps -> PV  (Ps reused across s;
        //      same-wave DS ordering makes that safe without barriers)
#pragma unroll
        for (int s = 0; s < 2; ++s) {
#pragma unroll
            for (int r = 0; r < 4; ++r) {
                float mx = fmaxf(fmaxf(S[s][0][r], S[s][1][r]), fmaxf(S[s][2][r], S[s][3][r]));
                mx = fmaxf(mx, __shfl_xor(mx, 1));
                mx = fmaxf(mx, __shfl_xor(mx, 2));
                mx = fmaxf(mx, __shfl_xor(mx, 4));
                mx = fmaxf(mx, __shfl_xor(mx, 8));
                const float mn = fmaxf(m[s][r], mx);
                const float al = __builtin_amdgcn_exp2f(m[s][r] - mn);
                m[s][r] = mn;
                float rs = 0.0f;
#pragma unroll
                for (int jt = 0; jt < 4; ++jt) {
                    const float p = __builtin_amdgcn_exp2f(S[s][jt][r] - mn);
                    Ps[w][(g * 4 + r) * 68 + jt * 16 + c] = f2bf(p);
                    rs += p;
                }
                rs += __shfl_xor(rs, 1); rs += __shfl_xor(rs, 2);
                rs += __shfl_xor(rs, 4); rs += __shfl_xor(rs, 8);
                l[s][r] = l[s][r] * al + rs;
#pragma unroll
                for (int dt = 0; dt < 4; ++dt) O[s][dt][r] *= al;
            }

#pragma unroll
            for (int jh = 0; jh < 2; ++jh) {
                bf16x8 ap = *(const bf16x8*)&Ps[w][c * 68 + jh * 32 + g * 8];
                __builtin_amdgcn_s_setprio(1);
#pragma unroll
                for (int dt = 0; dt < 4; ++dt) {
                    bf16x8 bv = *(const bf16x8*)&Vt[s][(dt * 16 + c) * 68
                                                      + jh * 32 + g * 8];
                    O[s][dt] = __builtin_amdgcn_mfma_f32_16x16x32_bf16(
                        ap, bv, O[s][dt], 0, 0, 0);
                }
                __builtin_amdgcn_s_setprio(0);
            }
        }
    }

    // ---- epilogue: Osum = O_ta/l_ta + O_tv/l_tv
    const size_t orow0 = kbase + (size_t)qb * 128 + w * 16;
#pragma unroll
    for (int dt = 0; dt < 4; ++dt)
#pragma unroll
        for (int r = 0; r < 4; ++r) {
            const float v = O[0][dt][r] / l[0][r] + O[1][dt][r] / l[1][r];
            Osum[(orow0 + g * 4 + r) * 1024 + hcol + dt * 16 + c] = f2bf(v);
        }
}

// ---------------------------------------------------------------------------
extern "C" void kernel_launch(void* const* d_in, const int* in_sizes, int n_in,
                              void* d_out, int out_size, void* d_ws, size_t ws_size,
                              hipStream_t stream)
{
    const void* h_t     = d_in[0];
    const void* h_a     = d_in[1];
    const void* h_v     = d_in[2];
    const void* h_hyper = d_in[3];
    const void* Wq      = d_in[4];
    const void* Wk_ta   = d_in[5];
    const void* Wk_tv   = d_in[6];
    const void* Wv_ta   = d_in[7];
    const void* Wv_tv   = d_in[8];
    const void* Wout    = d_in[9];
    const void* bout    = d_in[10];

    constexpr size_t MEG = (size_t)1024 * 1024;
    // header: flag at elem 0, boutC at elem 1024; payload starts at elem 4096
    int*      flag  = (int*)d_ws;
    ushort_t* boutC = (ushort_t*)d_ws + 1024;
    ushort_t* WT    = (ushort_t*)d_ws + 4096;

    detect_dtype<<<1, 256, 0, stream>>>((const unsigned int*)h_t, flag);
    conv_weights<<<dim3(16, 16, 6), 256, 0, stream>>>(
        Wq, Wk_ta, Wk_tv, Wv_ta, Wv_tv, Wout, WT, flag);
    conv_bout<<<1, 256, 0, stream>>>(bout, boutC, flag);

    // merged path needs: 4096 + 6M(WT) + 24M(ActC) + 40M(Pbuf) elements
    const size_t need_merged = (4096 + 70 * MEG) * sizeof(ushort_t);

    if (ws_size >= need_merged) {
        // ---- single pass over all 8 batches ----
        ushort_t* ActC = WT + 6 * MEG;          // 3 x 8M (h_t,h_a,h_v bf16)
        ushort_t* Pbuf = ActC + 24 * MEG;       // 5 x 8M projections
        ushort_t* OSg  = ActC;                  // alias: ActC dead after proj

        conv_act<<<dim3(4096, 3), 256, 0, stream>>>(
            h_t, h_a, h_v, 0, ActC, (long)(8 * MEG), flag);
        gemm_proj<<<dim3(8, 64, 5), 256, 0, stream>>>(
            ActC, WT, Pbuf, (long)(8 * MEG), (long)(8 * MEG));
        attn_fused<<<dim3(16, 8, 8), 512, 0, stream>>>(
            Pbuf,
            Pbuf + 8 * MEG,  Pbuf + 16 * MEG,
            Pbuf + 24 * MEG, Pbuf + 32 * MEG,
            OSg);
        gemm_out<<<dim3(8, 64), 256, 0, stream>>>(
            OSg, WT + 5 * MEG, h_hyper, 0, boutC, d_out, 0, flag);
    } else {
        // ---- fallback: 4 groups of 2 batches (same kernels, smaller grid) ----
        ushort_t* ActC = WT + 6 * MEG;          // 3 x 2M
        ushort_t* Pbuf = ActC + 6 * MEG;        // 5 x 2M
        ushort_t* OSg  = ActC;                  // alias: ActC dead after proj
        const long GSTRIDE = 2 * 1024 * 1024;
        for (int grp = 0; grp < 4; ++grp) {
            const long off = (long)grp * GSTRIDE;
            conv_act<<<dim3(1024, 3), 256, 0, stream>>>(
                h_t, h_a, h_v, off, ActC, (long)(2 * MEG), flag);
            gemm_proj<<<dim3(8, 16, 5), 256, 0, stream>>>(
                ActC, WT, Pbuf, (long)(2 * MEG), (long)(2 * MEG));
            attn_fused<<<dim3(16, 8, 2), 512, 0, stream>>>(
                Pbuf,
                Pbuf + 2 * MEG, Pbuf + 4 * MEG,
                Pbuf + 6 * MEG, Pbuf + 8 * MEG,
                OSg);
            gemm_out<<<dim3(8, 16), 256, 0, stream>>>(
                OSg, WT + 5 * MEG, h_hyper, off, boutC, d_out, off, flag);
        }
    }
}

// Round 6
// 540.495 us; speedup vs baseline: 1.8044x; 1.1164x over previous
//
#include <hip/hip_runtime.h>

typedef unsigned short ushort_t;
typedef __bf16 bf16_t;
typedef __bf16 bf16x8_b __attribute__((ext_vector_type(8)));
typedef bf16x8_b __attribute__((may_alias)) bf16x8;
typedef unsigned short u16x8_b __attribute__((ext_vector_type(8)));
typedef u16x8_b __attribute__((may_alias)) u16x8;
typedef unsigned short u16x4_b __attribute__((ext_vector_type(4)));
typedef u16x4_b __attribute__((may_alias)) u16x4;
typedef unsigned int u32x4_b __attribute__((ext_vector_type(4)));
typedef u32x4_b __attribute__((may_alias)) u32x4;
typedef float floatx4 __attribute__((ext_vector_type(4)));

__device__ __forceinline__ float bf2f(ushort_t h) {
    union { unsigned int u; float f; } v; v.u = ((unsigned int)h) << 16; return v.f;
}
__device__ __forceinline__ ushort_t f2bf(float f) {
    union { float f; unsigned int u; } v; v.f = f;
    unsigned int u = v.u;
    unsigned int r = (u + 0x7FFFu + ((u >> 16) & 1u)) >> 16;
    return (ushort_t)r;
}

// Async global->LDS DMA, 16B per lane. Dest must be wave-uniform base; HW adds
// lane*16. Completion tracked by vmcnt; __syncthreads() drains it.
__device__ __forceinline__ void glds16(const ushort_t* g, ushort_t* l) {
    __builtin_amdgcn_global_load_lds(
        (const __attribute__((address_space(1))) unsigned int*)g,
        (__attribute__((address_space(3))) unsigned int*)l, 16, 0, 0);
}

// ---------------------------------------------------------------------------
// Input dtype sniff: flag=1 means fp32 inputs.
// ---------------------------------------------------------------------------
__global__ __launch_bounds__(256) void detect_dtype(
    const unsigned int* __restrict__ x, int* __restrict__ flag)
{
    __shared__ int cnt;
    if (threadIdx.x == 0) cnt = 0;
    __syncthreads();
    int c = 0;
    for (int i = threadIdx.x; i < 512; i += 256) {
        unsigned int w = x[i];
        unsigned int e = (w >> 7) & 0xFFu;
        if (e >= 0x70u && e <= 0x8Fu) ++c;
    }
    atomicAdd(&cnt, c);
    __syncthreads();
    if (threadIdx.x == 0) *flag = (cnt < 256) ? 1 : 0;
}

// ---------------------------------------------------------------------------
// Transpose+convert 6 weights [1024,1024] -> WT[z][n][k] = bf16(W[k][n])
// ---------------------------------------------------------------------------
__global__ __launch_bounds__(256) void conv_weights(
    const void* __restrict__ w0, const void* __restrict__ w1,
    const void* __restrict__ w2, const void* __restrict__ w3,
    const void* __restrict__ w4, const void* __restrict__ w5,
    ushort_t* __restrict__ WT, const int* __restrict__ flag)
{
    __shared__ ushort_t t[64][65];
    const int z = blockIdx.z;
    const void* src = (z == 0) ? w0 : (z == 1) ? w1 : (z == 2) ? w2
                    : (z == 3) ? w3 : (z == 4) ? w4 : w5;
    const bool isf = (*flag != 0);
    ushort_t* dst = WT + (size_t)z * 1024 * 1024;
    const int x0 = blockIdx.x * 64, y0 = blockIdx.y * 64;
    const int tx = threadIdx.x & 63, ty0 = threadIdx.x >> 6;
#pragma unroll
    for (int r = 0; r < 16; ++r) {
        int ty = ty0 * 16 + r;
        size_t idx = (size_t)(y0 + ty) * 1024 + x0 + tx;
        t[ty][tx] = isf ? f2bf(((const float*)src)[idx]) : ((const ushort_t*)src)[idx];
    }
    __syncthreads();
#pragma unroll
    for (int r = 0; r < 16; ++r) {
        int ty = ty0 * 16 + r;
        dst[(size_t)(x0 + ty) * 1024 + y0 + tx] = t[tx][ty];
    }
}

__global__ __launch_bounds__(256) void conv_bout(
    const void* __restrict__ bout, ushort_t* __restrict__ dst,
    const int* __restrict__ flag)
{
    const bool isf = (*flag != 0);
    for (int i = threadIdx.x; i < 1024; i += 256)
        dst[i] = isf ? f2bf(((const float*)bout)[i]) : ((const ushort_t*)bout)[i];
}

// ---------------------------------------------------------------------------
// Convert a slice of {h_t,h_a,h_v} to bf16 in ws (h_hyper read raw later).
// ---------------------------------------------------------------------------
__global__ __launch_bounds__(256) void conv_act(
    const void* __restrict__ h_t, const void* __restrict__ h_a,
    const void* __restrict__ h_v,
    long off, ushort_t* __restrict__ ActC, long tstride,
    const int* __restrict__ flag)
{
    const int z = blockIdx.y;
    const void* s = (z == 0) ? h_t : (z == 1) ? h_a : h_v;
    const size_t e8 = ((size_t)blockIdx.x * 256 + threadIdx.x) * 8;
    ushort_t* dst = ActC + (size_t)z * tstride + e8;
    if (*flag) {
        const float* f = (const float*)s + off + e8;
        u32x4 o;
#pragma unroll
        for (int j = 0; j < 4; ++j) {
            unsigned int lo = f2bf(f[2 * j]);
            unsigned int hi = f2bf(f[2 * j + 1]);
            o[j] = lo | (hi << 16);
        }
        *(u32x4*)dst = o;
    } else {
        const ushort_t* b = (const ushort_t*)s + off + e8;
        *(u32x4*)dst = *(const u32x4*)b;
    }
}

// ---------------------------------------------------------------------------
// Core GEMM: C[M,1024] = A[M,1024] @ B, BT[1024,1024] given. Tile 128x128.
// Staging via global_load_lds width=16. Optional transposed bf16 output
// (tr=true): writes VT[b][gc][n] with b=gr>>10, n=gr&1023 — 8B stores of 4
// consecutive tokens. Used for the V projections so attention's PV step can
// read V^T with vector ds_read_b128 instead of scalar gathers.
// ---------------------------------------------------------------------------
__device__ __forceinline__ void gemm_core(
    const ushort_t* __restrict__ A, const ushort_t* __restrict__ BT,
    void* __restrict__ C, size_t ooff, bool f32o, bool tr,
    const void* __restrict__ addraw, long aoff,
    const ushort_t* __restrict__ bias, bool isf)
{
    constexpr int K = 1024, N = 1024;
    __shared__ __align__(16) ushort_t As[128 * 32];  // [m][k] linear
    __shared__ __align__(16) ushort_t Bs[128 * 32];  // [n][k] linear
    const int tid = threadIdx.x;
    const int w = tid >> 6, lane = tid & 63;
    const int g = lane >> 4, c = lane & 15;
    const int m0 = blockIdx.y * 128, n0 = blockIdx.x * 128;
    const int wm = (w >> 1) * 64, wn = (w & 1) * 64;

    const int srow = w * 32 + (lane >> 2);
    const int scol = (lane & 3) * 8;
    const ushort_t* Ag = A + (size_t)(m0 + srow) * K + scol;
    const ushort_t* Bg = BT + (size_t)(n0 + srow) * K + scol;
    ushort_t* AsW = &As[w * 1024];
    ushort_t* BsW = &Bs[w * 1024];

    floatx4 acc[4][4];
#pragma unroll
    for (int i = 0; i < 4; ++i)
#pragma unroll
        for (int j = 0; j < 4; ++j) acc[i][j] = (floatx4)0.0f;

    for (int k0 = 0; k0 < K; k0 += 32) {
        __syncthreads();
        glds16(Ag + k0,          AsW);
        glds16(Ag + k0 + 16 * K, AsW + 512);
        glds16(Bg + k0,          BsW);
        glds16(Bg + k0 + 16 * K, BsW + 512);
        __syncthreads();
        bf16x8 af[4], bfr[4];
#pragma unroll
        for (int i = 0; i < 4; ++i)
            af[i] = *(const bf16x8*)&As[(wm + i * 16 + c) * 32 + g * 8];
#pragma unroll
        for (int j = 0; j < 4; ++j)
            bfr[j] = *(const bf16x8*)&Bs[(wn + j * 16 + c) * 32 + g * 8];
#pragma unroll
        for (int i = 0; i < 4; ++i)
#pragma unroll
            for (int j = 0; j < 4; ++j)
                acc[i][j] = __builtin_amdgcn_mfma_f32_16x16x32_bf16(
                    af[i], bfr[j], acc[i][j], 0, 0, 0);
    }
#pragma unroll
    for (int i = 0; i < 4; ++i) {
#pragma unroll
        for (int j = 0; j < 4; ++j) {
            const int gc = n0 + wn + j * 16 + c;
            const int gr0 = m0 + wm + i * 16 + g * 4;
            if (tr) {
                // transposed bf16 store: VT[b][gc][n], 4 consecutive n
                u16x4 o4;
#pragma unroll
                for (int r = 0; r < 4; ++r) o4[r] = f2bf(acc[i][j][r]);
                const size_t ti = ((size_t)(gr0 >> 10) << 20)
                                + (size_t)gc * 1024 + (gr0 & 1023);
                *(u16x4*)&((ushort_t*)C)[ti] = o4;
            } else {
#pragma unroll
                for (int r = 0; r < 4; ++r) {
                    const int gr = gr0 + r;
                    float v = acc[i][j][r];
                    if (addraw) {
                        const size_t ai = (size_t)aoff + (size_t)gr * N + gc;
                        const float av = isf ? ((const float*)addraw)[ai]
                                             : bf2f(((const ushort_t*)addraw)[ai]);
                        v += av + bf2f(bias[gc]);
                    }
                    const size_t idx = ooff + (size_t)gr * N + gc;
                    if (f32o) ((float*)C)[idx] = v;
                    else      ((ushort_t*)C)[idx] = f2bf(v);
                }
            }
        }
    }
}

__global__ __launch_bounds__(256) void gemm_proj(
    const ushort_t* __restrict__ ActC, const ushort_t* __restrict__ WT,
    ushort_t* __restrict__ Pbuf, long astride, long pstride)
{
    const int z = blockIdx.z;
    const int asel = (z == 0) ? 0 : (z <= 2 ? 1 : 2);
    // WT order: 0 Wq, 1 Wk_ta, 2 Wk_tv, 3 Wv_ta, 4 Wv_tv, 5 Wout
    const int wsel = (z == 2) ? 3 : ((z == 3) ? 2 : z);
    const bool tr = (z == 2) || (z == 4);   // V projections -> transposed
    gemm_core(ActC + (size_t)asel * astride,
              WT + (size_t)wsel * 1024 * 1024,
              Pbuf + (size_t)z * pstride, 0, false, tr,
              nullptr, 0, nullptr, false);
}

__global__ __launch_bounds__(256) void gemm_out(
    const ushort_t* __restrict__ OutSum, const ushort_t* __restrict__ WoutT,
    const void* __restrict__ hyper_raw, long aoff,
    const ushort_t* __restrict__ boutC,
    void* __restrict__ out, long ooff, const int* __restrict__ flag)
{
    const bool isf = (*flag != 0);
    gemm_core(OutSum, WoutT, out, (size_t)ooff, isf, false,
              hyper_raw, aoff, boutC, isf);
}

// ---------------------------------------------------------------------------
// Fused dual-stream MFMA flash attention, round-11: swapped QK^T.
//  - S^T = mfma(K_frag, Q_frag): identical LDS reads/registers as before (the
//    A/B fragment layouts both want [row=c][k=g*8..7]); the verified C-layout
//    (col=lane&15, row=(lane>>4)*4+reg) then yields, for lane (c,g):
//    S^T[j=jt*16+g*4+r][q=c] — i.e. each lane holds 16 j-values of ONE q-row.
//  - softmax: row-max/sum = 15 in-reg VALU + 2 shfl (xor 16/32 over the 4
//    g-replicas); al transported to the O-row layout by __shfl(al, g*4+r).
//    shfl count per kt: 64 -> 16. m,l are scalars now.
//  - P store: 4 consecutive j per (jt) -> u16x4 b64 stores (4/stream vs 16
//    scalar); Ps stride 72 (b64 writes land 4 touches/bank = floor; b128 ap
//    reads 16B-aligned conflict-free, proven pattern).
//  - PV unchanged (V^T from gemm_proj, vector ds_read_b128; O rows q=g*4+r).
//  - V consumed from VT; all other structure as round-10.
// ---------------------------------------------------------------------------
__global__ __launch_bounds__(512) void attn_fused(
    const ushort_t* __restrict__ Qb,
    const ushort_t* __restrict__ Kta, const ushort_t* __restrict__ Vta,
    const ushort_t* __restrict__ Ktv, const ushort_t* __restrict__ Vtv,
    ushort_t* __restrict__ Osum)
{
    const int h = blockIdx.x, qb = blockIdx.y, lb = blockIdx.z;
    const int tid = threadIdx.x, w = tid >> 6, lane = tid & 63;
    const int g = lane >> 4, c = lane & 15;

    __shared__ __align__(16) ushort_t Ks[2][64 * 68];   // K tiles [j][d]
    __shared__ __align__(16) ushort_t Vt[2][64 * 68];   // V^T tiles [d][j]
    __shared__ __align__(16) ushort_t Ps[8][16 * 72];   // per-wave P [q][j]

    const float qscale = 0.125f * 1.44269504f;  // SCALE * log2(e)
    const size_t hcol = (size_t)h * 64;
    const size_t kbase = (size_t)lb * 1024;

    // staging coords: 512 threads cover 64 rows x 64 cols in one shot
    const int sj = tid >> 3;            // 0..63
    const int sd = (tid & 7) * 8;       // 0..56

    const ushort_t* Kp[2] = { Kta, Ktv };
    const ushort_t* Vv[2] = { Vta, Vtv };
    // VT row base for this (lb, h): VT[lb][hcol + sj][*]
    const size_t vrow = (size_t)lb * 1048576 + (hcol + sj) * 1024;

    // ---- prefetch kt=0 tiles into registers (in flight during Q setup)
    u32x4 pk[2], pv[2];
#pragma unroll
    for (int s = 0; s < 2; ++s) {
        pk[s] = *(const u32x4*)(Kp[s] + (kbase + sj) * 1024 + hcol + sd);
        pv[s] = *(const u32x4*)(Vv[s] + vrow + sd);
    }

    // ---- stage Q (128 rows) through Ks[0..1]; hoist pre-scaled fragments
    bf16x8 aq[2];
    {
        const size_t qrow0 = kbase + (size_t)qb * 128;
#pragma unroll
        for (int r = 0; r < 2; ++r)
            *(u32x4*)&Ks[r][sj * 68 + sd] =
                *(const u32x4*)(Qb + (qrow0 + r * 64 + sj) * 1024 + hcol + sd);
        __syncthreads();
        const int qbuf = w >> 2, qrow = (w & 3) * 16;
#pragma unroll
        for (int dh = 0; dh < 2; ++dh) {
            u16x8 raw = *(const u16x8*)&Ks[qbuf][(qrow + c) * 68 + dh * 32 + g * 8];
            u16x8 sc;
#pragma unroll
            for (int e = 0; e < 8; ++e) sc[e] = f2bf(bf2f(raw[e]) * qscale);
            aq[dh] = __builtin_bit_cast(bf16x8_b, (u16x8_b)sc);
        }
    }

    floatx4 O[2][4];
    float m[2], l[2];
#pragma unroll
    for (int s = 0; s < 2; ++s) {
#pragma unroll
        for (int dt = 0; dt < 4; ++dt) O[s][dt] = (floatx4)0.0f;
        m[s] = -1e30f; l[s] = 0.0f;
    }

    for (int kt = 0; kt < 16; ++kt) {
        __syncthreads();  // previous tile's LDS reads complete
#pragma unroll
        for (int s = 0; s < 2; ++s) {
            *(u32x4*)&Ks[s][sj * 68 + sd] = pk[s];
            *(u32x4*)&Vt[s][sj * 68 + sd] = pv[s];
        }
        if (kt < 15) {
            const size_t krow0 = kbase + (size_t)(kt + 1) * 64;
#pragma unroll
            for (int s = 0; s < 2; ++s) {
                pk[s] = *(const u32x4*)(Kp[s] + (krow0 + sj) * 1024 + hcol + sd);
                pv[s] = *(const u32x4*)(Vv[s] + vrow + (kt + 1) * 64 + sd);
            }
        }
        __syncthreads();  // tiles visible to all waves

        // ---- QK^T (swapped): S^T[j][q], both streams
        floatx4 S[2][4];
#pragma unroll
        for (int s = 0; s < 2; ++s)
#pragma unroll
            for (int jt = 0; jt < 4; ++jt) S[s][jt] = (floatx4)0.0f;
        __builtin_amdgcn_s_setprio(1);
#pragma unroll
        for (int s = 0; s < 2; ++s)
#pragma unroll
            for (int dh = 0; dh < 2; ++dh)
#pragma unroll
                for (int jt = 0; jt < 4; ++jt) {
                    bf16x8 bk = *(const bf16x8*)&Ks[s][(jt * 16 + c) * 68 + dh * 32 + g * 8];
                    S[s][jt] = __builtin_amdgcn_mfma_f32_16x16x32_bf16(
                        bk, aq[dh], S[s][jt], 0, 0, 0);
                }
        __builtin_amdgcn_s_setprio(0);

        // ---- per stream: lane-local softmax -> Ps (b64) -> PV
#pragma unroll
        for (int s = 0; s < 2; ++s) {
            // tile max over the 16 lane-local j-values + cross-g reduce
            float mx0 = fmaxf(fmaxf(S[s][0][0], S[s][0][1]),
                              fmaxf(S[s][0][2], S[s][0][3]));
            float mx1 = fmaxf(fmaxf(S[s][1][0], S[s][1][1]),
                              fmaxf(S[s][1][2], S[s][1][3]));
            float mx2 = fmaxf(fmaxf(S[s][2][0], S[s][2][1]),
                              fmaxf(S[s][2][2], S[s][2][3]));
            float mx3 = fmaxf(fmaxf(S[s][3][0], S[s][3][1]),
                              fmaxf(S[s][3][2], S[s][3][3]));
            float mx = fmaxf(fmaxf(mx0, mx1), fmaxf(mx2, mx3));
            mx = fmaxf(mx, __shfl_xor(mx, 16));
            mx = fmaxf(mx, __shfl_xor(mx, 32));
            const float mn = fmaxf(m[s], mx);
            const float al = __builtin_amdgcn_exp2f(m[s] - mn);
            m[s] = mn;
            float rs = 0.0f;
#pragma unroll
            for (int jt = 0; jt < 4; ++jt) {
                u16x4 pp;
#pragma unroll
                for (int r = 0; r < 4; ++r) {
                    const float p = __builtin_amdgcn_exp2f(S[s][jt][r] - mn);
                    rs += p;
                    pp[r] = f2bf(p);
                }
                *(u16x4*)&Ps[w][c * 72 + jt * 16 + g * 4] = pp;
            }
            rs += __shfl_xor(rs, 16);
            rs += __shfl_xor(rs, 32);
            l[s] = l[s] * al + rs;
            // transport al to the O-row layout (q = g*4+r) and rescale O
            float alq[4];
#pragma unroll
            for (int r = 0; r < 4; ++r) alq[r] = __shfl(al, g * 4 + r);
#pragma unroll
            for (int dt = 0; dt < 4; ++dt)
#pragma unroll
                for (int r = 0; r < 4; ++r) O[s][dt][r] *= alq[r];

            // PV: A = P[q=c][j-slice], B = V^T[d=c][j-slice]
#pragma unroll
            for (int jh = 0; jh < 2; ++jh) {
                bf16x8 ap = *(const bf16x8*)&Ps[w][c * 72 + jh * 32 + g * 8];
                __builtin_amdgcn_s_setprio(1);
#pragma unroll
                for (int dt = 0; dt < 4; ++dt) {
                    bf16x8 bv = *(const bf16x8*)&Vt[s][(dt * 16 + c) * 68
                                                      + jh * 32 + g * 8];
                    O[s][dt] = __builtin_amdgcn_mfma_f32_16x16x32_bf16(
                        ap, bv, O[s][dt], 0, 0, 0);
                }
                __builtin_amdgcn_s_setprio(0);
            }
        }
    }

    // ---- epilogue: transport l to O-row layout; Osum = O_ta/l + O_tv/l
    float lq0[4], lq1[4];
#pragma unroll
    for (int r = 0; r < 4; ++r) {
        lq0[r] = __shfl(l[0], g * 4 + r);
        lq1[r] = __shfl(l[1], g * 4 + r);
    }
    const size_t orow0 = kbase + (size_t)qb * 128 + w * 16;
#pragma unroll
    for (int dt = 0; dt < 4; ++dt)
#pragma unroll
        for (int r = 0; r < 4; ++r) {
            const float v = O[0][dt][r] / lq0[r] + O[1][dt][r] / lq1[r];
            Osum[(orow0 + g * 4 + r) * 1024 + hcol + dt * 16 + c] = f2bf(v);
        }
}

// ---------------------------------------------------------------------------
extern "C" void kernel_launch(void* const* d_in, const int* in_sizes, int n_in,
                              void* d_out, int out_size, void* d_ws, size_t ws_size,
                              hipStream_t stream)
{
    const void* h_t     = d_in[0];
    const void* h_a     = d_in[1];
    const void* h_v     = d_in[2];
    const void* h_hyper = d_in[3];
    const void* Wq      = d_in[4];
    const void* Wk_ta   = d_in[5];
    const void* Wk_tv   = d_in[6];
    const void* Wv_ta   = d_in[7];
    const void* Wv_tv   = d_in[8];
    const void* Wout    = d_in[9];
    const void* bout    = d_in[10];

    constexpr size_t MEG = (size_t)1024 * 1024;
    // header: flag at elem 0, boutC at elem 1024; payload starts at elem 4096
    int*      flag  = (int*)d_ws;
    ushort_t* boutC = (ushort_t*)d_ws + 1024;
    ushort_t* WT    = (ushort_t*)d_ws + 4096;

    detect_dtype<<<1, 256, 0, stream>>>((const unsigned int*)h_t, flag);
    conv_weights<<<dim3(16, 16, 6), 256, 0, stream>>>(
        Wq, Wk_ta, Wk_tv, Wv_ta, Wv_tv, Wout, WT, flag);
    conv_bout<<<1, 256, 0, stream>>>(bout, boutC, flag);

    // merged path needs: 4096 + 6M(WT) + 24M(ActC) + 40M(Pbuf) elements
    const size_t need_merged = (4096 + 70 * MEG) * sizeof(ushort_t);

    if (ws_size >= need_merged) {
        // ---- single pass over all 8 batches ----
        ushort_t* ActC = WT + 6 * MEG;          // 3 x 8M (h_t,h_a,h_v bf16)
        ushort_t* Pbuf = ActC + 24 * MEG;       // 5 x 8M projections
        ushort_t* OSg  = ActC;                  // alias: ActC dead after proj

        conv_act<<<dim3(4096, 3), 256, 0, stream>>>(
            h_t, h_a, h_v, 0, ActC, (long)(8 * MEG), flag);
        gemm_proj<<<dim3(8, 64, 5), 256, 0, stream>>>(
            ActC, WT, Pbuf, (long)(8 * MEG), (long)(8 * MEG));
        attn_fused<<<dim3(16, 8, 8), 512, 0, stream>>>(
            Pbuf,
            Pbuf + 8 * MEG,  Pbuf + 16 * MEG,
            Pbuf + 24 * MEG, Pbuf + 32 * MEG,
            OSg);
        gemm_out<<<dim3(8, 64), 256, 0, stream>>>(
            OSg, WT + 5 * MEG, h_hyper, 0, boutC, d_out, 0, flag);
    } else {
        // ---- fallback: 4 groups of 2 batches (same kernels, smaller grid) ----
        ushort_t* ActC = WT + 6 * MEG;          // 3 x 2M
        ushort_t* Pbuf = ActC + 6 * MEG;        // 5 x 2M
        ushort_t* OSg  = ActC;                  // alias: ActC dead after proj
        const long GSTRIDE = 2 * 1024 * 1024;
        for (int grp = 0; grp < 4; ++grp) {
            const long off = (long)grp * GSTRIDE;
            conv_act<<<dim3(1024, 3), 256, 0, stream>>>(
                h_t, h_a, h_v, off, ActC, (long)(2 * MEG), flag);
            gemm_proj<<<dim3(8, 16, 5), 256, 0, stream>>>(
                ActC, WT, Pbuf, (long)(2 * MEG), (long)(2 * MEG));
            attn_fused<<<dim3(16, 8, 2), 512, 0, stream>>>(
                Pbuf,
                Pbuf + 2 * MEG, Pbuf + 4 * MEG,
                Pbuf + 6 * MEG, Pbuf + 8 * MEG,
                OSg);
            gemm_out<<<dim3(8, 16), 256, 0, stream>>>(
                OSg, WT + 5 * MEG, h_hyper, off, boutC, d_out, off, flag);
        }
    }
}

// Round 7
// 521.882 us; speedup vs baseline: 1.8688x; 1.0357x over previous
//
#include <hip/hip_runtime.h>

typedef unsigned short ushort_t;
typedef __bf16 bf16_t;
typedef __bf16 bf16x8_b __attribute__((ext_vector_type(8)));
typedef bf16x8_b __attribute__((may_alias)) bf16x8;
typedef unsigned short u16x8_b __attribute__((ext_vector_type(8)));
typedef u16x8_b __attribute__((may_alias)) u16x8;
typedef unsigned short u16x4_b __attribute__((ext_vector_type(4)));
typedef u16x4_b __attribute__((may_alias)) u16x4;
typedef unsigned int u32x4_b __attribute__((ext_vector_type(4)));
typedef u32x4_b __attribute__((may_alias)) u32x4;
typedef float floatx4 __attribute__((ext_vector_type(4)));

__device__ __forceinline__ float bf2f(ushort_t h) {
    union { unsigned int u; float f; } v; v.u = ((unsigned int)h) << 16; return v.f;
}
__device__ __forceinline__ ushort_t f2bf(float f) {
    union { float f; unsigned int u; } v; v.f = f;
    unsigned int u = v.u;
    unsigned int r = (u + 0x7FFFu + ((u >> 16) & 1u)) >> 16;
    return (ushort_t)r;
}

// Async global->LDS DMA, 16B per lane. Dest must be wave-uniform base; HW adds
// lane*16. Completion tracked by vmcnt; __syncthreads() drains it.
__device__ __forceinline__ void glds16(const ushort_t* g, ushort_t* l) {
    __builtin_amdgcn_global_load_lds(
        (const __attribute__((address_space(1))) unsigned int*)g,
        (__attribute__((address_space(3))) unsigned int*)l, 16, 0, 0);
}

// ---------------------------------------------------------------------------
// Input dtype sniff: flag=1 means fp32 inputs.
// ---------------------------------------------------------------------------
__global__ __launch_bounds__(256) void detect_dtype(
    const unsigned int* __restrict__ x, int* __restrict__ flag)
{
    __shared__ int cnt;
    if (threadIdx.x == 0) cnt = 0;
    __syncthreads();
    int c = 0;
    for (int i = threadIdx.x; i < 512; i += 256) {
        unsigned int w = x[i];
        unsigned int e = (w >> 7) & 0xFFu;
        if (e >= 0x70u && e <= 0x8Fu) ++c;
    }
    atomicAdd(&cnt, c);
    __syncthreads();
    if (threadIdx.x == 0) *flag = (cnt < 256) ? 1 : 0;
}

// ---------------------------------------------------------------------------
// Transpose+convert 6 weights [1024,1024] -> WT[z][n][k] = bf16(W[k][n])
// ---------------------------------------------------------------------------
__global__ __launch_bounds__(256) void conv_weights(
    const void* __restrict__ w0, const void* __restrict__ w1,
    const void* __restrict__ w2, const void* __restrict__ w3,
    const void* __restrict__ w4, const void* __restrict__ w5,
    ushort_t* __restrict__ WT, const int* __restrict__ flag)
{
    __shared__ ushort_t t[64][65];
    const int z = blockIdx.z;
    const void* src = (z == 0) ? w0 : (z == 1) ? w1 : (z == 2) ? w2
                    : (z == 3) ? w3 : (z == 4) ? w4 : w5;
    const bool isf = (*flag != 0);
    ushort_t* dst = WT + (size_t)z * 1024 * 1024;
    const int x0 = blockIdx.x * 64, y0 = blockIdx.y * 64;
    const int tx = threadIdx.x & 63, ty0 = threadIdx.x >> 6;
#pragma unroll
    for (int r = 0; r < 16; ++r) {
        int ty = ty0 * 16 + r;
        size_t idx = (size_t)(y0 + ty) * 1024 + x0 + tx;
        t[ty][tx] = isf ? f2bf(((const float*)src)[idx]) : ((const ushort_t*)src)[idx];
    }
    __syncthreads();
#pragma unroll
    for (int r = 0; r < 16; ++r) {
        int ty = ty0 * 16 + r;
        dst[(size_t)(x0 + ty) * 1024 + y0 + tx] = t[tx][ty];
    }
}

__global__ __launch_bounds__(256) void conv_bout(
    const void* __restrict__ bout, ushort_t* __restrict__ dst,
    const int* __restrict__ flag)
{
    const bool isf = (*flag != 0);
    for (int i = threadIdx.x; i < 1024; i += 256)
        dst[i] = isf ? f2bf(((const float*)bout)[i]) : ((const ushort_t*)bout)[i];
}

// ---------------------------------------------------------------------------
// Convert a slice of {h_t,h_a,h_v} to bf16 in ws (h_hyper read raw later).
// ---------------------------------------------------------------------------
__global__ __launch_bounds__(256) void conv_act(
    const void* __restrict__ h_t, const void* __restrict__ h_a,
    const void* __restrict__ h_v,
    long off, ushort_t* __restrict__ ActC, long tstride,
    const int* __restrict__ flag)
{
    const int z = blockIdx.y;
    const void* s = (z == 0) ? h_t : (z == 1) ? h_a : h_v;
    const size_t e8 = ((size_t)blockIdx.x * 256 + threadIdx.x) * 8;
    ushort_t* dst = ActC + (size_t)z * tstride + e8;
    if (*flag) {
        const float* f = (const float*)s + off + e8;
        u32x4 o;
#pragma unroll
        for (int j = 0; j < 4; ++j) {
            unsigned int lo = f2bf(f[2 * j]);
            unsigned int hi = f2bf(f[2 * j + 1]);
            o[j] = lo | (hi << 16);
        }
        *(u32x4*)dst = o;
    } else {
        const ushort_t* b = (const ushort_t*)s + off + e8;
        *(u32x4*)dst = *(const u32x4*)b;
    }
}

// ---------------------------------------------------------------------------
// Core GEMM: C[M,1024] = A[M,1024] @ B, BT[1024,1024] given. Tile 128x128.
// Staging via global_load_lds width=16. Optional transposed bf16 output
// (tr=true): writes VT[b][gc][n] with b=gr>>10, n=gr&1023 — 8B stores of 4
// consecutive tokens. Used for the V projections so attention's PV step can
// read V^T with vector ds_read_b128 instead of scalar gathers.
// ---------------------------------------------------------------------------
__device__ __forceinline__ void gemm_core(
    const ushort_t* __restrict__ A, const ushort_t* __restrict__ BT,
    void* __restrict__ C, size_t ooff, bool f32o, bool tr,
    const void* __restrict__ addraw, long aoff,
    const ushort_t* __restrict__ bias, bool isf)
{
    constexpr int K = 1024, N = 1024;
    __shared__ __align__(16) ushort_t As[128 * 32];  // [m][k] linear
    __shared__ __align__(16) ushort_t Bs[128 * 32];  // [n][k] linear
    const int tid = threadIdx.x;
    const int w = tid >> 6, lane = tid & 63;
    const int g = lane >> 4, c = lane & 15;
    const int m0 = blockIdx.y * 128, n0 = blockIdx.x * 128;
    const int wm = (w >> 1) * 64, wn = (w & 1) * 64;

    const int srow = w * 32 + (lane >> 2);
    const int scol = (lane & 3) * 8;
    const ushort_t* Ag = A + (size_t)(m0 + srow) * K + scol;
    const ushort_t* Bg = BT + (size_t)(n0 + srow) * K + scol;
    ushort_t* AsW = &As[w * 1024];
    ushort_t* BsW = &Bs[w * 1024];

    floatx4 acc[4][4];
#pragma unroll
    for (int i = 0; i < 4; ++i)
#pragma unroll
        for (int j = 0; j < 4; ++j) acc[i][j] = (floatx4)0.0f;

    for (int k0 = 0; k0 < K; k0 += 32) {
        __syncthreads();
        glds16(Ag + k0,          AsW);
        glds16(Ag + k0 + 16 * K, AsW + 512);
        glds16(Bg + k0,          BsW);
        glds16(Bg + k0 + 16 * K, BsW + 512);
        __syncthreads();
        bf16x8 af[4], bfr[4];
#pragma unroll
        for (int i = 0; i < 4; ++i)
            af[i] = *(const bf16x8*)&As[(wm + i * 16 + c) * 32 + g * 8];
#pragma unroll
        for (int j = 0; j < 4; ++j)
            bfr[j] = *(const bf16x8*)&Bs[(wn + j * 16 + c) * 32 + g * 8];
#pragma unroll
        for (int i = 0; i < 4; ++i)
#pragma unroll
            for (int j = 0; j < 4; ++j)
                acc[i][j] = __builtin_amdgcn_mfma_f32_16x16x32_bf16(
                    af[i], bfr[j], acc[i][j], 0, 0, 0);
    }
#pragma unroll
    for (int i = 0; i < 4; ++i) {
#pragma unroll
        for (int j = 0; j < 4; ++j) {
            const int gc = n0 + wn + j * 16 + c;
            const int gr0 = m0 + wm + i * 16 + g * 4;
            if (tr) {
                // transposed bf16 store: VT[b][gc][n], 4 consecutive n
                u16x4 o4;
#pragma unroll
                for (int r = 0; r < 4; ++r) o4[r] = f2bf(acc[i][j][r]);
                const size_t ti = ((size_t)(gr0 >> 10) << 20)
                                + (size_t)gc * 1024 + (gr0 & 1023);
                *(u16x4*)&((ushort_t*)C)[ti] = o4;
            } else {
#pragma unroll
                for (int r = 0; r < 4; ++r) {
                    const int gr = gr0 + r;
                    float v = acc[i][j][r];
                    if (addraw) {
                        const size_t ai = (size_t)aoff + (size_t)gr * N + gc;
                        const float av = isf ? ((const float*)addraw)[ai]
                                             : bf2f(((const ushort_t*)addraw)[ai]);
                        v += av + bf2f(bias[gc]);
                    }
                    const size_t idx = ooff + (size_t)gr * N + gc;
                    if (f32o) ((float*)C)[idx] = v;
                    else      ((ushort_t*)C)[idx] = f2bf(v);
                }
            }
        }
    }
}

__global__ __launch_bounds__(256) void gemm_proj(
    const ushort_t* __restrict__ ActC, const ushort_t* __restrict__ WT,
    ushort_t* __restrict__ Pbuf, long astride, long pstride)
{
    const int z = blockIdx.z;
    const int asel = (z == 0) ? 0 : (z <= 2 ? 1 : 2);
    // WT order: 0 Wq, 1 Wk_ta, 2 Wk_tv, 3 Wv_ta, 4 Wv_tv, 5 Wout
    const int wsel = (z == 2) ? 3 : ((z == 3) ? 2 : z);
    const bool tr = (z == 2) || (z == 4);   // V projections -> transposed
    gemm_core(ActC + (size_t)asel * astride,
              WT + (size_t)wsel * 1024 * 1024,
              Pbuf + (size_t)z * pstride, 0, false, tr,
              nullptr, 0, nullptr, false);
}

__global__ __launch_bounds__(256) void gemm_out(
    const ushort_t* __restrict__ OutSum, const ushort_t* __restrict__ WoutT,
    const void* __restrict__ hyper_raw, long aoff,
    const ushort_t* __restrict__ boutC,
    void* __restrict__ out, long ooff, const int* __restrict__ flag)
{
    const bool isf = (*flag != 0);
    gemm_core(OutSum, WoutT, out, (size_t)ooff, isf, false,
              hyper_raw, aoff, boutC, isf);
}

// ---------------------------------------------------------------------------
// Fused dual-stream MFMA flash attention, round-12:
//  - swapped QK^T (R6): lane-local softmax rows; shfl 64 -> 16 per kt
//  - Ps stride back to 68 (R5's MEASURED zero-conflict read pattern;
//    stride-72 made ap reads 8-way / writes 4-way: 6.29e6 conflicts in R6).
//    b64 P-writes kept (136c ≡ 0 mod 8 -> 8B aligned).
//  - T13 defer-max THR=8: skip {m update, al exp2, al-broadcast shfl,
//    O-rescale} when the tile max hasn't exceeded m+8 (wave-uniform __all).
//    P then bounded by 2^8 — fine in bf16 (floating relative precision).
//  - V consumed from VT (d-major from gemm_proj); all else as R6.
// ---------------------------------------------------------------------------
__global__ __launch_bounds__(512) void attn_fused(
    const ushort_t* __restrict__ Qb,
    const ushort_t* __restrict__ Kta, const ushort_t* __restrict__ Vta,
    const ushort_t* __restrict__ Ktv, const ushort_t* __restrict__ Vtv,
    ushort_t* __restrict__ Osum)
{
    const int h = blockIdx.x, qb = blockIdx.y, lb = blockIdx.z;
    const int tid = threadIdx.x, w = tid >> 6, lane = tid & 63;
    const int g = lane >> 4, c = lane & 15;

    __shared__ __align__(16) ushort_t Ks[2][64 * 68];   // K tiles [j][d]
    __shared__ __align__(16) ushort_t Vt[2][64 * 68];   // V^T tiles [d][j]
    __shared__ __align__(16) ushort_t Ps[8][16 * 68];   // per-wave P [q][j]

    const float qscale = 0.125f * 1.44269504f;  // SCALE * log2(e)
    const size_t hcol = (size_t)h * 64;
    const size_t kbase = (size_t)lb * 1024;

    // staging coords: 512 threads cover 64 rows x 64 cols in one shot
    const int sj = tid >> 3;            // 0..63
    const int sd = (tid & 7) * 8;       // 0..56

    const ushort_t* Kp[2] = { Kta, Ktv };
    const ushort_t* Vv[2] = { Vta, Vtv };
    // VT row base for this (lb, h): VT[lb][hcol + sj][*]
    const size_t vrow = (size_t)lb * 1048576 + (hcol + sj) * 1024;

    // ---- prefetch kt=0 tiles into registers (in flight during Q setup)
    u32x4 pk[2], pv[2];
#pragma unroll
    for (int s = 0; s < 2; ++s) {
        pk[s] = *(const u32x4*)(Kp[s] + (kbase + sj) * 1024 + hcol + sd);
        pv[s] = *(const u32x4*)(Vv[s] + vrow + sd);
    }

    // ---- stage Q (128 rows) through Ks[0..1]; hoist pre-scaled fragments
    bf16x8 aq[2];
    {
        const size_t qrow0 = kbase + (size_t)qb * 128;
#pragma unroll
        for (int r = 0; r < 2; ++r)
            *(u32x4*)&Ks[r][sj * 68 + sd] =
                *(const u32x4*)(Qb + (qrow0 + r * 64 + sj) * 1024 + hcol + sd);
        __syncthreads();
        const int qbuf = w >> 2, qrow = (w & 3) * 16;
#pragma unroll
        for (int dh = 0; dh < 2; ++dh) {
            u16x8 raw = *(const u16x8*)&Ks[qbuf][(qrow + c) * 68 + dh * 32 + g * 8];
            u16x8 sc;
#pragma unroll
            for (int e = 0; e < 8; ++e) sc[e] = f2bf(bf2f(raw[e]) * qscale);
            aq[dh] = __builtin_bit_cast(bf16x8_b, (u16x8_b)sc);
        }
    }

    floatx4 O[2][4];
    float m[2], l[2];
#pragma unroll
    for (int s = 0; s < 2; ++s) {
#pragma unroll
        for (int dt = 0; dt < 4; ++dt) O[s][dt] = (floatx4)0.0f;
        m[s] = -1e30f; l[s] = 0.0f;
    }

    for (int kt = 0; kt < 16; ++kt) {
        __syncthreads();  // previous tile's LDS reads complete
#pragma unroll
        for (int s = 0; s < 2; ++s) {
            *(u32x4*)&Ks[s][sj * 68 + sd] = pk[s];
            *(u32x4*)&Vt[s][sj * 68 + sd] = pv[s];
        }
        if (kt < 15) {
            const size_t krow0 = kbase + (size_t)(kt + 1) * 64;
#pragma unroll
            for (int s = 0; s < 2; ++s) {
                pk[s] = *(const u32x4*)(Kp[s] + (krow0 + sj) * 1024 + hcol + sd);
                pv[s] = *(const u32x4*)(Vv[s] + vrow + (kt + 1) * 64 + sd);
            }
        }
        __syncthreads();  // tiles visible to all waves

        // ---- QK^T (swapped): S^T[j][q], both streams
        floatx4 S[2][4];
#pragma unroll
        for (int s = 0; s < 2; ++s)
#pragma unroll
            for (int jt = 0; jt < 4; ++jt) S[s][jt] = (floatx4)0.0f;
        __builtin_amdgcn_s_setprio(1);
#pragma unroll
        for (int s = 0; s < 2; ++s)
#pragma unroll
            for (int dh = 0; dh < 2; ++dh)
#pragma unroll
                for (int jt = 0; jt < 4; ++jt) {
                    bf16x8 bk = *(const bf16x8*)&Ks[s][(jt * 16 + c) * 68 + dh * 32 + g * 8];
                    S[s][jt] = __builtin_amdgcn_mfma_f32_16x16x32_bf16(
                        bk, aq[dh], S[s][jt], 0, 0, 0);
                }
        __builtin_amdgcn_s_setprio(0);

        // ---- per stream: lane-local softmax (defer-max) -> Ps (b64) -> PV
#pragma unroll
        for (int s = 0; s < 2; ++s) {
            // tile max over the 16 lane-local j-values + cross-g reduce
            float mx0 = fmaxf(fmaxf(S[s][0][0], S[s][0][1]),
                              fmaxf(S[s][0][2], S[s][0][3]));
            float mx1 = fmaxf(fmaxf(S[s][1][0], S[s][1][1]),
                              fmaxf(S[s][1][2], S[s][1][3]));
            float mx2 = fmaxf(fmaxf(S[s][2][0], S[s][2][1]),
                              fmaxf(S[s][2][2], S[s][2][3]));
            float mx3 = fmaxf(fmaxf(S[s][3][0], S[s][3][1]),
                              fmaxf(S[s][3][2], S[s][3][3]));
            float mx = fmaxf(fmaxf(mx0, mx1), fmaxf(mx2, mx3));
            mx = fmaxf(mx, __shfl_xor(mx, 16));
            mx = fmaxf(mx, __shfl_xor(mx, 32));

            // T13 defer-max: only rescale when the tile max grew past m+8.
            const bool need = !__all(mx - m[s] <= 8.0f);
            float mn = m[s];
            if (need) mn = fmaxf(m[s], mx);

            float rs = 0.0f;
#pragma unroll
            for (int jt = 0; jt < 4; ++jt) {
                u16x4 pp;
#pragma unroll
                for (int r = 0; r < 4; ++r) {
                    const float p = __builtin_amdgcn_exp2f(S[s][jt][r] - mn);
                    rs += p;
                    pp[r] = f2bf(p);
                }
                *(u16x4*)&Ps[w][c * 68 + jt * 16 + g * 4] = pp;
            }
            rs += __shfl_xor(rs, 16);
            rs += __shfl_xor(rs, 32);

            if (need) {
                const float al = __builtin_amdgcn_exp2f(m[s] - mn);
                m[s] = mn;
                l[s] = l[s] * al + rs;
                float alq[4];
#pragma unroll
                for (int r = 0; r < 4; ++r) alq[r] = __shfl(al, g * 4 + r);
#pragma unroll
                for (int dt = 0; dt < 4; ++dt)
#pragma unroll
                    for (int r = 0; r < 4; ++r) O[s][dt][r] *= alq[r];
            } else {
                l[s] += rs;
            }

            // PV: A = P[q=c][j-slice], B = V^T[d=c][j-slice]
#pragma unroll
            for (int jh = 0; jh < 2; ++jh) {
                bf16x8 ap = *(const bf16x8*)&Ps[w][c * 68 + jh * 32 + g * 8];
                __builtin_amdgcn_s_setprio(1);
#pragma unroll
                for (int dt = 0; dt < 4; ++dt) {
                    bf16x8 bv = *(const bf16x8*)&Vt[s][(dt * 16 + c) * 68
                                                      + jh * 32 + g * 8];
                    O[s][dt] = __builtin_amdgcn_mfma_f32_16x16x32_bf16(
                        ap, bv, O[s][dt], 0, 0, 0);
                }
                __builtin_amdgcn_s_setprio(0);
            }
        }
    }

    // ---- epilogue: transport l to O-row layout; Osum = O_ta/l + O_tv/l
    float lq0[4], lq1[4];
#pragma unroll
    for (int r = 0; r < 4; ++r) {
        lq0[r] = __shfl(l[0], g * 4 + r);
        lq1[r] = __shfl(l[1], g * 4 + r);
    }
    const size_t orow0 = kbase + (size_t)qb * 128 + w * 16;
#pragma unroll
    for (int dt = 0; dt < 4; ++dt)
#pragma unroll
        for (int r = 0; r < 4; ++r) {
            const float v = O[0][dt][r] / lq0[r] + O[1][dt][r] / lq1[r];
            Osum[(orow0 + g * 4 + r) * 1024 + hcol + dt * 16 + c] = f2bf(v);
        }
}

// ---------------------------------------------------------------------------
extern "C" void kernel_launch(void* const* d_in, const int* in_sizes, int n_in,
                              void* d_out, int out_size, void* d_ws, size_t ws_size,
                              hipStream_t stream)
{
    const void* h_t     = d_in[0];
    const void* h_a     = d_in[1];
    const void* h_v     = d_in[2];
    const void* h_hyper = d_in[3];
    const void* Wq      = d_in[4];
    const void* Wk_ta   = d_in[5];
    const void* Wk_tv   = d_in[6];
    const void* Wv_ta   = d_in[7];
    const void* Wv_tv   = d_in[8];
    const void* Wout    = d_in[9];
    const void* bout    = d_in[10];

    constexpr size_t MEG = (size_t)1024 * 1024;
    // header: flag at elem 0, boutC at elem 1024; payload starts at elem 4096
    int*      flag  = (int*)d_ws;
    ushort_t* boutC = (ushort_t*)d_ws + 1024;
    ushort_t* WT    = (ushort_t*)d_ws + 4096;

    detect_dtype<<<1, 256, 0, stream>>>((const unsigned int*)h_t, flag);
    conv_weights<<<dim3(16, 16, 6), 256, 0, stream>>>(
        Wq, Wk_ta, Wk_tv, Wv_ta, Wv_tv, Wout, WT, flag);
    conv_bout<<<1, 256, 0, stream>>>(bout, boutC, flag);

    // merged path needs: 4096 + 6M(WT) + 24M(ActC) + 40M(Pbuf) elements
    const size_t need_merged = (4096 + 70 * MEG) * sizeof(ushort_t);

    if (ws_size >= need_merged) {
        // ---- single pass over all 8 batches ----
        ushort_t* ActC = WT + 6 * MEG;          // 3 x 8M (h_t,h_a,h_v bf16)
        ushort_t* Pbuf = ActC + 24 * MEG;       // 5 x 8M projections
        ushort_t* OSg  = ActC;                  // alias: ActC dead after proj

        conv_act<<<dim3(4096, 3), 256, 0, stream>>>(
            h_t, h_a, h_v, 0, ActC, (long)(8 * MEG), flag);
        gemm_proj<<<dim3(8, 64, 5), 256, 0, stream>>>(
            ActC, WT, Pbuf, (long)(8 * MEG), (long)(8 * MEG));
        attn_fused<<<dim3(16, 8, 8), 512, 0, stream>>>(
            Pbuf,
            Pbuf + 8 * MEG,  Pbuf + 16 * MEG,
            Pbuf + 24 * MEG, Pbuf + 32 * MEG,
            OSg);
        gemm_out<<<dim3(8, 64), 256, 0, stream>>>(
            OSg, WT + 5 * MEG, h_hyper, 0, boutC, d_out, 0, flag);
    } else {
        // ---- fallback: 4 groups of 2 batches (same kernels, smaller grid) ----
        ushort_t* ActC = WT + 6 * MEG;          // 3 x 2M
        ushort_t* Pbuf = ActC + 6 * MEG;        // 5 x 2M
        ushort_t* OSg  = ActC;                  // alias: ActC dead after proj
        const long GSTRIDE = 2 * 1024 * 1024;
        for (int grp = 0; grp < 4; ++grp) {
            const long off = (long)grp * GSTRIDE;
            conv_act<<<dim3(1024, 3), 256, 0, stream>>>(
                h_t, h_a, h_v, off, ActC, (long)(2 * MEG), flag);
            gemm_proj<<<dim3(8, 16, 5), 256, 0, stream>>>(
                ActC, WT, Pbuf, (long)(2 * MEG), (long)(2 * MEG));
            attn_fused<<<dim3(16, 8, 2), 512, 0, stream>>>(
                Pbuf,
                Pbuf + 2 * MEG, Pbuf + 4 * MEG,
                Pbuf + 6 * MEG, Pbuf + 8 * MEG,
                OSg);
            gemm_out<<<dim3(8, 16), 256, 0, stream>>>(
                OSg, WT + 5 * MEG, h_hyper, off, boutC, d_out, off, flag);
        }
    }
}

// Round 8
// 503.940 us; speedup vs baseline: 1.9353x; 1.0356x over previous
//
#include <hip/hip_runtime.h>

typedef unsigned short ushort_t;
typedef __bf16 bf16_t;
typedef __bf16 bf16x8_b __attribute__((ext_vector_type(8)));
typedef bf16x8_b __attribute__((may_alias)) bf16x8;
typedef unsigned short u16x8_b __attribute__((ext_vector_type(8)));
typedef u16x8_b __attribute__((may_alias)) u16x8;
typedef unsigned short u16x4_b __attribute__((ext_vector_type(4)));
typedef u16x4_b __attribute__((may_alias)) u16x4;
typedef unsigned int u32x4_b __attribute__((ext_vector_type(4)));
typedef u32x4_b __attribute__((may_alias)) u32x4;
typedef float floatx4 __attribute__((ext_vector_type(4)));

__device__ __forceinline__ float bf2f(ushort_t h) {
    union { unsigned int u; float f; } v; v.u = ((unsigned int)h) << 16; return v.f;
}
__device__ __forceinline__ ushort_t f2bf(float f) {
    union { float f; unsigned int u; } v; v.f = f;
    unsigned int u = v.u;
    unsigned int r = (u + 0x7FFFu + ((u >> 16) & 1u)) >> 16;
    return (ushort_t)r;
}

// Async global->LDS DMA, 16B per lane. Dest must be wave-uniform base; HW adds
// lane*16. Completion tracked by vmcnt; __syncthreads() drains it.
__device__ __forceinline__ void glds16(const ushort_t* g, ushort_t* l) {
    __builtin_amdgcn_global_load_lds(
        (const __attribute__((address_space(1))) unsigned int*)g,
        (__attribute__((address_space(3))) unsigned int*)l, 16, 0, 0);
}

// ---------------------------------------------------------------------------
// Input dtype sniff: flag=1 means fp32 inputs.
// ---------------------------------------------------------------------------
__global__ __launch_bounds__(256) void detect_dtype(
    const unsigned int* __restrict__ x, int* __restrict__ flag)
{
    __shared__ int cnt;
    if (threadIdx.x == 0) cnt = 0;
    __syncthreads();
    int c = 0;
    for (int i = threadIdx.x; i < 512; i += 256) {
        unsigned int w = x[i];
        unsigned int e = (w >> 7) & 0xFFu;
        if (e >= 0x70u && e <= 0x8Fu) ++c;
    }
    atomicAdd(&cnt, c);
    __syncthreads();
    if (threadIdx.x == 0) *flag = (cnt < 256) ? 1 : 0;
}

// ---------------------------------------------------------------------------
// Transpose+convert 6 weights [1024,1024] -> WT[z][n][k] = bf16(W[k][n])
// ---------------------------------------------------------------------------
__global__ __launch_bounds__(256) void conv_weights(
    const void* __restrict__ w0, const void* __restrict__ w1,
    const void* __restrict__ w2, const void* __restrict__ w3,
    const void* __restrict__ w4, const void* __restrict__ w5,
    ushort_t* __restrict__ WT, const int* __restrict__ flag)
{
    __shared__ ushort_t t[64][65];
    const int z = blockIdx.z;
    const void* src = (z == 0) ? w0 : (z == 1) ? w1 : (z == 2) ? w2
                    : (z == 3) ? w3 : (z == 4) ? w4 : w5;
    const bool isf = (*flag != 0);
    ushort_t* dst = WT + (size_t)z * 1024 * 1024;
    const int x0 = blockIdx.x * 64, y0 = blockIdx.y * 64;
    const int tx = threadIdx.x & 63, ty0 = threadIdx.x >> 6;
#pragma unroll
    for (int r = 0; r < 16; ++r) {
        int ty = ty0 * 16 + r;
        size_t idx = (size_t)(y0 + ty) * 1024 + x0 + tx;
        t[ty][tx] = isf ? f2bf(((const float*)src)[idx]) : ((const ushort_t*)src)[idx];
    }
    __syncthreads();
#pragma unroll
    for (int r = 0; r < 16; ++r) {
        int ty = ty0 * 16 + r;
        dst[(size_t)(x0 + ty) * 1024 + y0 + tx] = t[tx][ty];
    }
}

__global__ __launch_bounds__(256) void conv_bout(
    const void* __restrict__ bout, ushort_t* __restrict__ dst,
    const int* __restrict__ flag)
{
    const bool isf = (*flag != 0);
    for (int i = threadIdx.x; i < 1024; i += 256)
        dst[i] = isf ? f2bf(((const float*)bout)[i]) : ((const ushort_t*)bout)[i];
}

// ---------------------------------------------------------------------------
// Convert a slice of {h_t,h_a,h_v} to bf16 in ws (h_hyper read raw later).
// ---------------------------------------------------------------------------
__global__ __launch_bounds__(256) void conv_act(
    const void* __restrict__ h_t, const void* __restrict__ h_a,
    const void* __restrict__ h_v,
    long off, ushort_t* __restrict__ ActC, long tstride,
    const int* __restrict__ flag)
{
    const int z = blockIdx.y;
    const void* s = (z == 0) ? h_t : (z == 1) ? h_a : h_v;
    const size_t e8 = ((size_t)blockIdx.x * 256 + threadIdx.x) * 8;
    ushort_t* dst = ActC + (size_t)z * tstride + e8;
    if (*flag) {
        const float* f = (const float*)s + off + e8;
        u32x4 o;
#pragma unroll
        for (int j = 0; j < 4; ++j) {
            unsigned int lo = f2bf(f[2 * j]);
            unsigned int hi = f2bf(f[2 * j + 1]);
            o[j] = lo | (hi << 16);
        }
        *(u32x4*)dst = o;
    } else {
        const ushort_t* b = (const ushort_t*)s + off + e8;
        *(u32x4*)dst = *(const u32x4*)b;
    }
}

// ---------------------------------------------------------------------------
// Core GEMM: C[M,1024] = A[M,1024] @ B, BT[1024,1024] given. Tile 128x128.
// Staging via global_load_lds width=16.
// Round-13: grid axes swapped (x = m-tile, y = n-tile). Linear dispatch id =
// (z*gy + y)*gx + x with gx ≡ 0 mod 8 gives id%8 = x%8, so all blocks sharing
// an A m-panel land on ONE XCD -> A-panel HBM-fetched once per XCD instead of
// 8x (R7: ~640MB A traffic in gemm_proj, the gap to the structure's ~900TF).
// Optional transposed bf16 output (tr=true) for the V projections.
// ---------------------------------------------------------------------------
__device__ __forceinline__ void gemm_core(
    const ushort_t* __restrict__ A, const ushort_t* __restrict__ BT,
    void* __restrict__ C, size_t ooff, bool f32o, bool tr,
    const void* __restrict__ addraw, long aoff,
    const ushort_t* __restrict__ bias, bool isf)
{
    constexpr int K = 1024, N = 1024;
    __shared__ __align__(16) ushort_t As[128 * 32];  // [m][k] linear
    __shared__ __align__(16) ushort_t Bs[128 * 32];  // [n][k] linear
    const int tid = threadIdx.x;
    const int w = tid >> 6, lane = tid & 63;
    const int g = lane >> 4, c = lane & 15;
    const int m0 = blockIdx.x * 128, n0 = blockIdx.y * 128;   // swapped (T1)
    const int wm = (w >> 1) * 64, wn = (w & 1) * 64;

    const int srow = w * 32 + (lane >> 2);
    const int scol = (lane & 3) * 8;
    const ushort_t* Ag = A + (size_t)(m0 + srow) * K + scol;
    const ushort_t* Bg = BT + (size_t)(n0 + srow) * K + scol;
    ushort_t* AsW = &As[w * 1024];
    ushort_t* BsW = &Bs[w * 1024];

    floatx4 acc[4][4];
#pragma unroll
    for (int i = 0; i < 4; ++i)
#pragma unroll
        for (int j = 0; j < 4; ++j) acc[i][j] = (floatx4)0.0f;

    for (int k0 = 0; k0 < K; k0 += 32) {
        __syncthreads();
        glds16(Ag + k0,          AsW);
        glds16(Ag + k0 + 16 * K, AsW + 512);
        glds16(Bg + k0,          BsW);
        glds16(Bg + k0 + 16 * K, BsW + 512);
        __syncthreads();
        bf16x8 af[4], bfr[4];
#pragma unroll
        for (int i = 0; i < 4; ++i)
            af[i] = *(const bf16x8*)&As[(wm + i * 16 + c) * 32 + g * 8];
#pragma unroll
        for (int j = 0; j < 4; ++j)
            bfr[j] = *(const bf16x8*)&Bs[(wn + j * 16 + c) * 32 + g * 8];
#pragma unroll
        for (int i = 0; i < 4; ++i)
#pragma unroll
            for (int j = 0; j < 4; ++j)
                acc[i][j] = __builtin_amdgcn_mfma_f32_16x16x32_bf16(
                    af[i], bfr[j], acc[i][j], 0, 0, 0);
    }
#pragma unroll
    for (int i = 0; i < 4; ++i) {
#pragma unroll
        for (int j = 0; j < 4; ++j) {
            const int gc = n0 + wn + j * 16 + c;
            const int gr0 = m0 + wm + i * 16 + g * 4;
            if (tr) {
                // transposed bf16 store: VT[b][gc][n], 4 consecutive n
                u16x4 o4;
#pragma unroll
                for (int r = 0; r < 4; ++r) o4[r] = f2bf(acc[i][j][r]);
                const size_t ti = ((size_t)(gr0 >> 10) << 20)
                                + (size_t)gc * 1024 + (gr0 & 1023);
                *(u16x4*)&((ushort_t*)C)[ti] = o4;
            } else {
#pragma unroll
                for (int r = 0; r < 4; ++r) {
                    const int gr = gr0 + r;
                    float v = acc[i][j][r];
                    if (addraw) {
                        const size_t ai = (size_t)aoff + (size_t)gr * N + gc;
                        const float av = isf ? ((const float*)addraw)[ai]
                                             : bf2f(((const ushort_t*)addraw)[ai]);
                        v += av + bf2f(bias[gc]);
                    }
                    const size_t idx = ooff + (size_t)gr * N + gc;
                    if (f32o) ((float*)C)[idx] = v;
                    else      ((ushort_t*)C)[idx] = f2bf(v);
                }
            }
        }
    }
}

__global__ __launch_bounds__(256) void gemm_proj(
    const ushort_t* __restrict__ ActC, const ushort_t* __restrict__ WT,
    ushort_t* __restrict__ Pbuf, long astride, long pstride)
{
    const int z = blockIdx.z;
    const int asel = (z == 0) ? 0 : (z <= 2 ? 1 : 2);
    // WT order: 0 Wq, 1 Wk_ta, 2 Wk_tv, 3 Wv_ta, 4 Wv_tv, 5 Wout
    const int wsel = (z == 2) ? 3 : ((z == 3) ? 2 : z);
    const bool tr = (z == 2) || (z == 4);   // V projections -> transposed
    gemm_core(ActC + (size_t)asel * astride,
              WT + (size_t)wsel * 1024 * 1024,
              Pbuf + (size_t)z * pstride, 0, false, tr,
              nullptr, 0, nullptr, false);
}

__global__ __launch_bounds__(256) void gemm_out(
    const ushort_t* __restrict__ OutSum, const ushort_t* __restrict__ WoutT,
    const void* __restrict__ hyper_raw, long aoff,
    const ushort_t* __restrict__ boutC,
    void* __restrict__ out, long ooff, const int* __restrict__ flag)
{
    const bool isf = (*flag != 0);
    gemm_core(OutSum, WoutT, out, (size_t)ooff, isf, false,
              hyper_raw, aoff, boutC, isf);
}

// ---------------------------------------------------------------------------
// Fused dual-stream MFMA flash attention, round-12 (unchanged from R7 pass):
//  - swapped QK^T: lane-local softmax rows; shfl 64 -> 16 per kt
//  - Ps stride 68 (measured zero-conflict); b64 P-writes
//  - T13 defer-max THR=8
//  - V consumed from VT (d-major from gemm_proj)
// ---------------------------------------------------------------------------
__global__ __launch_bounds__(512) void attn_fused(
    const ushort_t* __restrict__ Qb,
    const ushort_t* __restrict__ Kta, const ushort_t* __restrict__ Vta,
    const ushort_t* __restrict__ Ktv, const ushort_t* __restrict__ Vtv,
    ushort_t* __restrict__ Osum)
{
    const int h = blockIdx.x, qb = blockIdx.y, lb = blockIdx.z;
    const int tid = threadIdx.x, w = tid >> 6, lane = tid & 63;
    const int g = lane >> 4, c = lane & 15;

    __shared__ __align__(16) ushort_t Ks[2][64 * 68];   // K tiles [j][d]
    __shared__ __align__(16) ushort_t Vt[2][64 * 68];   // V^T tiles [d][j]
    __shared__ __align__(16) ushort_t Ps[8][16 * 68];   // per-wave P [q][j]

    const float qscale = 0.125f * 1.44269504f;  // SCALE * log2(e)
    const size_t hcol = (size_t)h * 64;
    const size_t kbase = (size_t)lb * 1024;

    // staging coords: 512 threads cover 64 rows x 64 cols in one shot
    const int sj = tid >> 3;            // 0..63
    const int sd = (tid & 7) * 8;       // 0..56

    const ushort_t* Kp[2] = { Kta, Ktv };
    const ushort_t* Vv[2] = { Vta, Vtv };
    // VT row base for this (lb, h): VT[lb][hcol + sj][*]
    const size_t vrow = (size_t)lb * 1048576 + (hcol + sj) * 1024;

    // ---- prefetch kt=0 tiles into registers (in flight during Q setup)
    u32x4 pk[2], pv[2];
#pragma unroll
    for (int s = 0; s < 2; ++s) {
        pk[s] = *(const u32x4*)(Kp[s] + (kbase + sj) * 1024 + hcol + sd);
        pv[s] = *(const u32x4*)(Vv[s] + vrow + sd);
    }

    // ---- stage Q (128 rows) through Ks[0..1]; hoist pre-scaled fragments
    bf16x8 aq[2];
    {
        const size_t qrow0 = kbase + (size_t)qb * 128;
#pragma unroll
        for (int r = 0; r < 2; ++r)
            *(u32x4*)&Ks[r][sj * 68 + sd] =
                *(const u32x4*)(Qb + (qrow0 + r * 64 + sj) * 1024 + hcol + sd);
        __syncthreads();
        const int qbuf = w >> 2, qrow = (w & 3) * 16;
#pragma unroll
        for (int dh = 0; dh < 2; ++dh) {
            u16x8 raw = *(const u16x8*)&Ks[qbuf][(qrow + c) * 68 + dh * 32 + g * 8];
            u16x8 sc;
#pragma unroll
            for (int e = 0; e < 8; ++e) sc[e] = f2bf(bf2f(raw[e]) * qscale);
            aq[dh] = __builtin_bit_cast(bf16x8_b, (u16x8_b)sc);
        }
    }

    floatx4 O[2][4];
    float m[2], l[2];
#pragma unroll
    for (int s = 0; s < 2; ++s) {
#pragma unroll
        for (int dt = 0; dt < 4; ++dt) O[s][dt] = (floatx4)0.0f;
        m[s] = -1e30f; l[s] = 0.0f;
    }

    for (int kt = 0; kt < 16; ++kt) {
        __syncthreads();  // previous tile's LDS reads complete
#pragma unroll
        for (int s = 0; s < 2; ++s) {
            *(u32x4*)&Ks[s][sj * 68 + sd] = pk[s];
            *(u32x4*)&Vt[s][sj * 68 + sd] = pv[s];
        }
        if (kt < 15) {
            const size_t krow0 = kbase + (size_t)(kt + 1) * 64;
#pragma unroll
            for (int s = 0; s < 2; ++s) {
                pk[s] = *(const u32x4*)(Kp[s] + (krow0 + sj) * 1024 + hcol + sd);
                pv[s] = *(const u32x4*)(Vv[s] + vrow + (kt + 1) * 64 + sd);
            }
        }
        __syncthreads();  // tiles visible to all waves

        // ---- QK^T (swapped): S^T[j][q], both streams
        floatx4 S[2][4];
#pragma unroll
        for (int s = 0; s < 2; ++s)
#pragma unroll
            for (int jt = 0; jt < 4; ++jt) S[s][jt] = (floatx4)0.0f;
        __builtin_amdgcn_s_setprio(1);
#pragma unroll
        for (int s = 0; s < 2; ++s)
#pragma unroll
            for (int dh = 0; dh < 2; ++dh)
#pragma unroll
                for (int jt = 0; jt < 4; ++jt) {
                    bf16x8 bk = *(const bf16x8*)&Ks[s][(jt * 16 + c) * 68 + dh * 32 + g * 8];
                    S[s][jt] = __builtin_amdgcn_mfma_f32_16x16x32_bf16(
                        bk, aq[dh], S[s][jt], 0, 0, 0);
                }
        __builtin_amdgcn_s_setprio(0);

        // ---- per stream: lane-local softmax (defer-max) -> Ps (b64) -> PV
#pragma unroll
        for (int s = 0; s < 2; ++s) {
            // tile max over the 16 lane-local j-values + cross-g reduce
            float mx0 = fmaxf(fmaxf(S[s][0][0], S[s][0][1]),
                              fmaxf(S[s][0][2], S[s][0][3]));
            float mx1 = fmaxf(fmaxf(S[s][1][0], S[s][1][1]),
                              fmaxf(S[s][1][2], S[s][1][3]));
            float mx2 = fmaxf(fmaxf(S[s][2][0], S[s][2][1]),
                              fmaxf(S[s][2][2], S[s][2][3]));
            float mx3 = fmaxf(fmaxf(S[s][3][0], S[s][3][1]),
                              fmaxf(S[s][3][2], S[s][3][3]));
            float mx = fmaxf(fmaxf(mx0, mx1), fmaxf(mx2, mx3));
            mx = fmaxf(mx, __shfl_xor(mx, 16));
            mx = fmaxf(mx, __shfl_xor(mx, 32));

            // T13 defer-max: only rescale when the tile max grew past m+8.
            const bool need = !__all(mx - m[s] <= 8.0f);
            float mn = m[s];
            if (need) mn = fmaxf(m[s], mx);

            float rs = 0.0f;
#pragma unroll
            for (int jt = 0; jt < 4; ++jt) {
                u16x4 pp;
#pragma unroll
                for (int r = 0; r < 4; ++r) {
                    const float p = __builtin_amdgcn_exp2f(S[s][jt][r] - mn);
                    rs += p;
                    pp[r] = f2bf(p);
                }
                *(u16x4*)&Ps[w][c * 68 + jt * 16 + g * 4] = pp;
            }
            rs += __shfl_xor(rs, 16);
            rs += __shfl_xor(rs, 32);

            if (need) {
                const float al = __builtin_amdgcn_exp2f(m[s] - mn);
                m[s] = mn;
                l[s] = l[s] * al + rs;
                float alq[4];
#pragma unroll
                for (int r = 0; r < 4; ++r) alq[r] = __shfl(al, g * 4 + r);
#pragma unroll
                for (int dt = 0; dt < 4; ++dt)
#pragma unroll
                    for (int r = 0; r < 4; ++r) O[s][dt][r] *= alq[r];
            } else {
                l[s] += rs;
            }

            // PV: A = P[q=c][j-slice], B = V^T[d=c][j-slice]
#pragma unroll
            for (int jh = 0; jh < 2; ++jh) {
                bf16x8 ap = *(const bf16x8*)&Ps[w][c * 68 + jh * 32 + g * 8];
                __builtin_amdgcn_s_setprio(1);
#pragma unroll
                for (int dt = 0; dt < 4; ++dt) {
                    bf16x8 bv = *(const bf16x8*)&Vt[s][(dt * 16 + c) * 68
                                                      + jh * 32 + g * 8];
                    O[s][dt] = __builtin_amdgcn_mfma_f32_16x16x32_bf16(
                        ap, bv, O[s][dt], 0, 0, 0);
                }
                __builtin_amdgcn_s_setprio(0);
            }
        }
    }

    // ---- epilogue: transport l to O-row layout; Osum = O_ta/l + O_tv/l
    float lq0[4], lq1[4];
#pragma unroll
    for (int r = 0; r < 4; ++r) {
        lq0[r] = __shfl(l[0], g * 4 + r);
        lq1[r] = __shfl(l[1], g * 4 + r);
    }
    const size_t orow0 = kbase + (size_t)qb * 128 + w * 16;
#pragma unroll
    for (int dt = 0; dt < 4; ++dt)
#pragma unroll
        for (int r = 0; r < 4; ++r) {
            const float v = O[0][dt][r] / lq0[r] + O[1][dt][r] / lq1[r];
            Osum[(orow0 + g * 4 + r) * 1024 + hcol + dt * 16 + c] = f2bf(v);
        }
}

// ---------------------------------------------------------------------------
extern "C" void kernel_launch(void* const* d_in, const int* in_sizes, int n_in,
                              void* d_out, int out_size, void* d_ws, size_t ws_size,
                              hipStream_t stream)
{
    const void* h_t     = d_in[0];
    const void* h_a     = d_in[1];
    const void* h_v     = d_in[2];
    const void* h_hyper = d_in[3];
    const void* Wq      = d_in[4];
    const void* Wk_ta   = d_in[5];
    const void* Wk_tv   = d_in[6];
    const void* Wv_ta   = d_in[7];
    const void* Wv_tv   = d_in[8];
    const void* Wout    = d_in[9];
    const void* bout    = d_in[10];

    constexpr size_t MEG = (size_t)1024 * 1024;
    // header: flag at elem 0, boutC at elem 1024; payload starts at elem 4096
    int*      flag  = (int*)d_ws;
    ushort_t* boutC = (ushort_t*)d_ws + 1024;
    ushort_t* WT    = (ushort_t*)d_ws + 4096;

    detect_dtype<<<1, 256, 0, stream>>>((const unsigned int*)h_t, flag);
    conv_weights<<<dim3(16, 16, 6), 256, 0, stream>>>(
        Wq, Wk_ta, Wk_tv, Wv_ta, Wv_tv, Wout, WT, flag);
    conv_bout<<<1, 256, 0, stream>>>(bout, boutC, flag);

    // merged path needs: 4096 + 6M(WT) + 24M(ActC) + 40M(Pbuf) elements
    const size_t need_merged = (4096 + 70 * MEG) * sizeof(ushort_t);

    if (ws_size >= need_merged) {
        // ---- single pass over all 8 batches ----
        ushort_t* ActC = WT + 6 * MEG;          // 3 x 8M (h_t,h_a,h_v bf16)
        ushort_t* Pbuf = ActC + 24 * MEG;       // 5 x 8M projections
        ushort_t* OSg  = ActC;                  // alias: ActC dead after proj

        conv_act<<<dim3(4096, 3), 256, 0, stream>>>(
            h_t, h_a, h_v, 0, ActC, (long)(8 * MEG), flag);
        gemm_proj<<<dim3(64, 8, 5), 256, 0, stream>>>(
            ActC, WT, Pbuf, (long)(8 * MEG), (long)(8 * MEG));
        attn_fused<<<dim3(16, 8, 8), 512, 0, stream>>>(
            Pbuf,
            Pbuf + 8 * MEG,  Pbuf + 16 * MEG,
            Pbuf + 24 * MEG, Pbuf + 32 * MEG,
            OSg);
        gemm_out<<<dim3(64, 8), 256, 0, stream>>>(
            OSg, WT + 5 * MEG, h_hyper, 0, boutC, d_out, 0, flag);
    } else {
        // ---- fallback: 4 groups of 2 batches (same kernels, smaller grid) ----
        ushort_t* ActC = WT + 6 * MEG;          // 3 x 2M
        ushort_t* Pbuf = ActC + 6 * MEG;        // 5 x 2M
        ushort_t* OSg  = ActC;                  // alias: ActC dead after proj
        const long GSTRIDE = 2 * 1024 * 1024;
        for (int grp = 0; grp < 4; ++grp) {
            const long off = (long)grp * GSTRIDE;
            conv_act<<<dim3(1024, 3), 256, 0, stream>>>(
                h_t, h_a, h_v, off, ActC, (long)(2 * MEG), flag);
            gemm_proj<<<dim3(16, 8, 5), 256, 0, stream>>>(
                ActC, WT, Pbuf, (long)(2 * MEG), (long)(2 * MEG));
            attn_fused<<<dim3(16, 8, 2), 512, 0, stream>>>(
                Pbuf,
                Pbuf + 2 * MEG, Pbuf + 4 * MEG,
                Pbuf + 6 * MEG, Pbuf + 8 * MEG,
                OSg);
            gemm_out<<<dim3(16, 8), 256, 0, stream>>>(
                OSg, WT + 5 * MEG, h_hyper, off, boutC, d_out, off, flag);
        }
    }
}